// Round 1
// baseline (1572.135 us; speedup 1.0000x reference)
//
#include <hip/hip_runtime.h>
#include <cstdint>

#define S_LEN 4096
#define NHEAD 8
#define DHEAD 128
#define DMODEL 1024
#define NTOK 8192
#define MOBA_TOPK 4

typedef __attribute__((ext_vector_type(8))) short short8;
typedef __attribute__((ext_vector_type(4))) float f32x4;

__device__ inline float bf2f(short s) {
  return __builtin_bit_cast(float, (unsigned)((unsigned short)s) << 16);
}
__device__ inline short f2bf(float f) {
  unsigned u = __builtin_bit_cast(unsigned, f);
  unsigned r = (u + 0x7fffu + ((u >> 16) & 1u)) >> 16;
  return (short)(unsigned short)r;
}
__device__ inline float toF(float v) { return v; }
__device__ inline float toF(short v) { return bf2f(v); }

#define MFMA(a, b, c) __builtin_amdgcn_mfma_f32_16x16x32_bf16(a, b, c, 0, 0, 0)
#define GLOAD_LDS(gsrc, ldst)                                                  \
  __builtin_amdgcn_global_load_lds(                                            \
      (const __attribute__((address_space(1))) void*)(gsrc),                   \
      (__attribute__((address_space(3))) void*)(ldst), 16, 0, 0)

// ---------------------------------------------------------------- transpose
// in: [R,C] (batched), out: [C,R] bf16
template <typename T>
__global__ __launch_bounds__(256) void transpose_bf16(const T* __restrict__ in,
                                                      short* __restrict__ out,
                                                      int R, int C) {
  __shared__ float tile[32][33];
  size_t bo = (size_t)blockIdx.z * R * C;
  int c0 = blockIdx.x * 32, r0 = blockIdx.y * 32;
  int tx = threadIdx.x & 31, ty = threadIdx.x >> 5;
#pragma unroll
  for (int i = 0; i < 32; i += 8)
    tile[ty + i][tx] = toF(in[bo + (size_t)(r0 + ty + i) * C + c0 + tx]);
  __syncthreads();
#pragma unroll
  for (int i = 0; i < 32; i += 8)
    out[bo + (size_t)(c0 + ty + i) * R + r0 + tx] = f2bf(tile[tx][ty + i]);
}

// ---------------------------------------------------------------- layernorm
// x: fp32 [rows, 1024] -> out bf16. one wave per row.
__global__ __launch_bounds__(256) void ln_kernel(const float* __restrict__ x,
                                                 const float* __restrict__ w,
                                                 const float* __restrict__ b,
                                                 short* __restrict__ out) {
  int row = blockIdx.x * 4 + (threadIdx.x >> 6);
  int lane = threadIdx.x & 63;
  const float* xr = x + (size_t)row * DMODEL + lane * 16;
  f32x4 v[4];
  float sum = 0.f, sq = 0.f;
#pragma unroll
  for (int i = 0; i < 4; ++i) {
    v[i] = *(const f32x4*)(xr + i * 4);
#pragma unroll
    for (int j = 0; j < 4; ++j) {
      sum += v[i][j];
      sq += v[i][j] * v[i][j];
    }
  }
#pragma unroll
  for (int d = 1; d < 64; d <<= 1) {
    sum += __shfl_xor(sum, d, 64);
    sq += __shfl_xor(sq, d, 64);
  }
  float mu = sum * (1.f / DMODEL);
  float var = sq * (1.f / DMODEL) - mu * mu;
  float rstd = rsqrtf(var + 1e-5f);
  short* orow = out + (size_t)row * DMODEL;
#pragma unroll
  for (int i = 0; i < 4; ++i)
#pragma unroll
    for (int j = 0; j < 4; ++j) {
      int c = lane * 16 + i * 4 + j;
      orow[c] = f2bf((v[i][j] - mu) * rstd * w[c] + b[c]);
    }
}

// ---------------------------------------------------------------- GEMM
// C[M,N] = A[M,K](bf16) * BT[N,K]^T (bf16) + bias
// MODE 0: scatter bf16 -> [B,H,S,DH]
// MODE 1: fp32 out = acc + bias + residF   (O-proj + residual)
// MODE 2: bf16 out = gelu(acc + bias)      (FFN1)
// MODE 3: fp32 outF += acc + bias          (FFN2 + residual, in place)
template <int MODE>
__global__ __launch_bounds__(256) void gemm128(const short* __restrict__ A,
                                               const short* __restrict__ BT,
                                               const float* __restrict__ bias,
                                               const float* __restrict__ residF,
                                               short* __restrict__ outB,
                                               float* outF, int M, int N,
                                               int K) {
  __shared__ alignas(16) short As[4096];
  __shared__ alignas(16) short Bs[4096];
  const int t = threadIdx.x;
  const int lane = t & 63, w = t >> 6;
  const int wm = w >> 1, wn = w & 1;
  const int m0 = blockIdx.y * 128, n0 = blockIdx.x * 128;

  const f32x4 fz = {0.f, 0.f, 0.f, 0.f};
  f32x4 acc[4][4];
#pragma unroll
  for (int i = 0; i < 4; ++i)
#pragma unroll
    for (int j = 0; j < 4; ++j) acc[i][j] = fz;

  // staging map: thread t -> row (t>>6)*16+(t&15) of 64-row half, k-chunk (t>>4)&3
  const int sm = ((t >> 6) << 4) + (t & 15);
  const int sk = ((t >> 4) & 3) << 3;
  const short* gA0 = A + (size_t)(m0 + sm) * K + sk;
  const short* gA1 = A + (size_t)(m0 + 64 + sm) * K + sk;
  const short* gB0 = BT + (size_t)(n0 + sm) * K + sk;
  const short* gB1 = BT + (size_t)(n0 + 64 + sm) * K + sk;

  for (int k0 = 0; k0 < K; k0 += 32) {
    GLOAD_LDS(gA0 + k0, As + t * 8);
    GLOAD_LDS(gA1 + k0, As + 2048 + t * 8);
    GLOAD_LDS(gB0 + k0, Bs + t * 8);
    GLOAD_LDS(gB1 + k0, Bs + 2048 + t * 8);
    __syncthreads();
    short8 af[4], bf[4];
#pragma unroll
    for (int mi = 0; mi < 4; ++mi)
      af[mi] = *(const short8*)(As + ((wm * 4 + mi) << 9) + lane * 8);
#pragma unroll
    for (int ni = 0; ni < 4; ++ni)
      bf[ni] = *(const short8*)(Bs + ((wn * 4 + ni) << 9) + lane * 8);
#pragma unroll
    for (int mi = 0; mi < 4; ++mi)
#pragma unroll
      for (int ni = 0; ni < 4; ++ni)
        acc[mi][ni] = MFMA(af[mi], bf[ni], acc[mi][ni]);
    __syncthreads();
  }

  const int er = lane >> 4, ec = lane & 15;
#pragma unroll
  for (int mi = 0; mi < 4; ++mi) {
#pragma unroll
    for (int ni = 0; ni < 4; ++ni) {
      int col = n0 + wn * 64 + ni * 16 + ec;
      float bs = bias[col];
#pragma unroll
      for (int r = 0; r < 4; ++r) {
        int row = m0 + wm * 64 + mi * 16 + er * 4 + r;
        float v = acc[mi][ni][r] + bs;
        size_t idx = (size_t)row * N + col;
        if (MODE == 0) {
          int b = row >> 12, s = row & 4095;
          int h = col >> 7, dh = col & 127;
          outB[((size_t)((b * NHEAD + h) * S_LEN + s)) * DHEAD + dh] = f2bf(v);
        } else if (MODE == 1) {
          v += residF[idx];
          outF[idx] = v;
        } else if (MODE == 2) {
          float gl = 0.5f * v * (1.f + erff(v * 0.70710678118654752f));
          outB[idx] = f2bf(gl);
        } else {
          v += outF[idx];
          outF[idx] = v;
        }
      }
    }
  }
}

// ---------------------------------------------------------------- RoPE
// q,k: [16, S, 128] bf16 in place. one wave per (head,s) row.
__global__ __launch_bounds__(256) void rope_kernel(short* __restrict__ q,
                                                   short* __restrict__ k,
                                                   const float* __restrict__ cosT,
                                                   const float* __restrict__ sinT) {
  int row = blockIdx.x * 4 + (threadIdx.x >> 6);
  int lane = threadIdx.x & 63;
  int s = row & (S_LEN - 1);
  float c1 = cosT[s * DHEAD + lane], s1 = sinT[s * DHEAD + lane];
  float c2 = cosT[s * DHEAD + 64 + lane], s2 = sinT[s * DHEAD + 64 + lane];
  size_t base = (size_t)row * DHEAD;
  float a = bf2f(q[base + lane]), bb = bf2f(q[base + 64 + lane]);
  q[base + lane] = f2bf(a * c1 - bb * s1);
  q[base + 64 + lane] = f2bf(bb * c2 + a * s2);
  a = bf2f(k[base + lane]);
  bb = bf2f(k[base + 64 + lane]);
  k[base + lane] = f2bf(a * c1 - bb * s1);
  k[base + 64 + lane] = f2bf(bb * c2 + a * s2);
}

// ---------------------------------------------------------------- kmean
__global__ __launch_bounds__(256) void kmean_kernel(const short* __restrict__ K,
                                                    float* __restrict__ kmean) {
  int n = blockIdx.x, bh = blockIdx.y;
  int t = threadIdx.x;
  int d = t & 127, half = t >> 7;
  const short* base = K + ((size_t)bh * S_LEN + n * 512 + half * 256) * DHEAD + d;
  float s = 0.f;
  for (int i = 0; i < 256; ++i) s += bf2f(base[(size_t)i * DHEAD]);
  __shared__ float red[256];
  red[t] = s;
  __syncthreads();
  if (t < 128)
    kmean[((size_t)bh * 8 + n) * DHEAD + d] = (red[t] + red[t + 128]) * (1.f / 512.f);
}

// ---------------------------------------------------------------- gate / topk
__global__ __launch_bounds__(256) void gate_kernel(const short* __restrict__ Q,
                                                   const float* __restrict__ kmean,
                                                   unsigned* __restrict__ selmask) {
  int bh = blockIdx.x >> 4;
  int s = ((blockIdx.x & 15) << 8) + threadIdx.x;
  __shared__ float km[8 * DHEAD];
  for (int i = threadIdx.x; i < 8 * DHEAD; i += 256)
    km[i] = kmean[(size_t)bh * 8 * DHEAD + i];
  __syncthreads();
  const short* qrow = Q + ((size_t)bh * S_LEN + s) * DHEAD;
  float g[8] = {0, 0, 0, 0, 0, 0, 0, 0};
  for (int c = 0; c < 16; ++c) {
    short8 qv = *(const short8*)(qrow + c * 8);
    float qf[8];
#pragma unroll
    for (int j = 0; j < 8; ++j) qf[j] = bf2f(qv[j]);
#pragma unroll
    for (int n = 0; n < 8; ++n) {
      float a = 0.f;
#pragma unroll
      for (int j = 0; j < 8; ++j) a += qf[j] * km[n * DHEAD + c * 8 + j];
      g[n] += a;
    }
  }
  int own = s >> 9;
  int nvis = own + 1;
  int kcnt = nvis < MOBA_TOPK ? nvis : MOBA_TOPK;
  unsigned used = 0;
  for (int it = 0; it < kcnt; ++it) {
    float best = -1e38f;
    int bi = 0;
    for (int n = 0; n < nvis; ++n)
      if (!((used >> n) & 1) && g[n] > best) {
        best = g[n];
        bi = n;
      }
    used |= 1u << bi;
  }
  selmask[(size_t)bh * S_LEN + s] = used | (1u << own);
}

// ---------------------------------------------------------------- attention
// 4 waves/block, 16 queries/wave, 32-key subtiles, block-sparse + causal mask.
__global__ __launch_bounds__(256) void attn_kernel(
    const short* __restrict__ Q, const short* __restrict__ K,
    const short* __restrict__ VT, const unsigned* __restrict__ selmask,
    short* __restrict__ out) {
  const int qt = blockIdx.x, bh = blockIdx.y;
  const int b = bh >> 3, h = bh & 7;
  const int q0t = qt << 6;
  const int t = threadIdx.x, lane = t & 63, w = t >> 6;
  const int qblk = q0t >> 9;
  const int er = lane >> 4, ec = lane & 15;

  __shared__ unsigned selS[64];
  __shared__ unsigned unionS[1];
  __shared__ alignas(16) short Plds[4][640];  // 16 rows x 40 (padded) per wave

  if (t < 64) selS[t] = selmask[(size_t)bh * S_LEN + q0t + t];
  __syncthreads();
  if (t == 0) {
    unsigned u = 0;
    for (int i = 0; i < 64; ++i) u |= selS[i];
    unionS[0] = u;
  }
  __syncthreads();
  const unsigned um = unionS[0];

  const size_t sbh = (size_t)bh * S_LEN * DHEAD;
  const int q0w = q0t + w * 16;

  short8 qf[4];
#pragma unroll
  for (int ks = 0; ks < 4; ++ks)
    qf[ks] = *(const short8*)(Q + sbh + (size_t)(q0w + ec) * DHEAD + ks * 32 + er * 8);

  const f32x4 fz = {0.f, 0.f, 0.f, 0.f};
  f32x4 oacc[8];
#pragma unroll
  for (int n = 0; n < 8; ++n) oacc[n] = fz;
  float mrow[4] = {-1e30f, -1e30f, -1e30f, -1e30f};
  float lrow[4] = {0.f, 0.f, 0.f, 0.f};
  const float scale = 0.088388347648318447f;  // 1/sqrt(128)
  const int qmaxt = q0t + 63;
  short* pl = &Plds[w][0];

  for (int kb = 0; kb < 8; ++kb) {
    if (!((um >> kb) & 1)) continue;
    const int kbase = kb << 9;
    bool selr[4];
#pragma unroll
    for (int r = 0; r < 4; ++r)
      selr[r] = (selS[w * 16 + er * 4 + r] >> kb) & 1;
    int nsub = (kb == qblk) ? (((qmaxt - kbase) >> 5) + 1) : 16;
    for (int kt = 0; kt < nsub; ++kt) {
      const int key0 = kbase + (kt << 5);
      f32x4 sc0 = fz, sc1 = fz;
#pragma unroll
      for (int ks = 0; ks < 4; ++ks) {
        short8 kf0 = *(const short8*)(K + sbh + (size_t)(key0 + ec) * DHEAD + ks * 32 + er * 8);
        short8 kf1 = *(const short8*)(K + sbh + (size_t)(key0 + 16 + ec) * DHEAD + ks * 32 + er * 8);
        sc0 = MFMA(qf[ks], kf0, sc0);
        sc1 = MFMA(qf[ks], kf1, sc1);
      }
      float p0[4], p1[4], corr[4];
#pragma unroll
      for (int r = 0; r < 4; ++r) {
        const int qq = q0w + er * 4 + r;
        float s0 = sc0[r] * scale, s1 = sc1[r] * scale;
        const bool ok0 = selr[r] && (key0 + ec) <= qq;
        const bool ok1 = selr[r] && (key0 + 16 + ec) <= qq;
        s0 = ok0 ? s0 : -1e30f;
        s1 = ok1 ? s1 : -1e30f;
        float mx = fmaxf(s0, s1);
#pragma unroll
        for (int d = 1; d < 16; d <<= 1) mx = fmaxf(mx, __shfl_xor(mx, d, 64));
        const float mnew = fmaxf(mrow[r], mx);
        const float c = __expf(mrow[r] - mnew);
        const float e0 = ok0 ? __expf(s0 - mnew) : 0.f;
        const float e1 = ok1 ? __expf(s1 - mnew) : 0.f;
        float rs = e0 + e1;
#pragma unroll
        for (int d = 1; d < 16; d <<= 1) rs += __shfl_xor(rs, d, 64);
        lrow[r] = lrow[r] * c + rs;
        mrow[r] = mnew;
        corr[r] = c;
        p0[r] = e0;
        p1[r] = e1;
      }
#pragma unroll
      for (int n = 0; n < 8; ++n)
#pragma unroll
        for (int r = 0; r < 4; ++r) oacc[n][r] *= corr[r];
#pragma unroll
      for (int r = 0; r < 4; ++r) {
        const int prow = er * 4 + r;
        pl[prow * 40 + ec] = f2bf(p0[r]);
        pl[prow * 40 + 16 + ec] = f2bf(p1[r]);
      }
      asm volatile("s_waitcnt lgkmcnt(0)" ::: "memory");
      const short8 pa = *(const short8*)(pl + ec * 40 + er * 8);
#pragma unroll
      for (int n = 0; n < 8; ++n) {
        short8 vf = *(const short8*)(VT + ((size_t)bh * DHEAD + n * 16 + ec) * S_LEN + key0 + er * 8);
        oacc[n] = MFMA(pa, vf, oacc[n]);
      }
    }
  }
#pragma unroll
  for (int n = 0; n < 8; ++n) {
#pragma unroll
    for (int r = 0; r < 4; ++r) {
      const int qq = q0w + er * 4 + r;
      float v = oacc[n][r] / lrow[r];
      out[((size_t)(b * S_LEN + qq)) * DMODEL + h * DHEAD + n * 16 + ec] = f2bf(v);
    }
  }
}

// ---------------------------------------------------------------- launcher
extern "C" void kernel_launch(void* const* d_in, const int* in_sizes, int n_in,
                              void* d_out, int out_size, void* d_ws,
                              size_t ws_size, hipStream_t stream) {
  (void)in_sizes; (void)n_in; (void)out_size; (void)ws_size;
  const float* hidden = (const float*)d_in[0];
  const float* ln1w = (const float*)d_in[1];
  const float* ln1b = (const float*)d_in[2];
  const float* wq = (const float*)d_in[3];
  const float* bq = (const float*)d_in[4];
  const float* wk = (const float*)d_in[5];
  const float* bk = (const float*)d_in[6];
  const float* wv = (const float*)d_in[7];
  const float* bv = (const float*)d_in[8];
  const float* wo = (const float*)d_in[9];
  const float* bo = (const float*)d_in[10];
  const float* ln2w = (const float*)d_in[11];
  const float* ln2b = (const float*)d_in[12];
  const float* wi = (const float*)d_in[13];
  const float* bi = (const float*)d_in[14];
  const float* wo2 = (const float*)d_in[15];
  const float* bo2 = (const float*)d_in[16];
  const float* cosT = (const float*)d_in[17];
  const float* sinT = (const float*)d_in[18];
  float* outF = (float*)d_out;

  char* base = (char*)d_ws;
  size_t off = 0;
  auto alloc = [&](size_t bytes) {
    char* p = base + off;
    off = (off + bytes + 255) & ~(size_t)255;
    return p;
  };
  short* wqT = (short*)alloc((size_t)1024 * 1024 * 2);
  short* wkT = (short*)alloc((size_t)1024 * 1024 * 2);
  short* wvT = (short*)alloc((size_t)1024 * 1024 * 2);
  short* woT = (short*)alloc((size_t)1024 * 1024 * 2);
  short* wiT = (short*)alloc((size_t)4096 * 1024 * 2);
  short* wo2T = (short*)alloc((size_t)1024 * 4096 * 2);
  float* kmeanB = (float*)alloc((size_t)16 * 8 * 128 * 4);
  unsigned* selm = (unsigned*)alloc((size_t)16 * 4096 * 4);
  short* xattn = (short*)alloc((size_t)8192 * 1024 * 2);
  short* h2 = (short*)alloc((size_t)8192 * 1024 * 2);
  size_t phase = off;  // region below is reusable after attention
  short* xln = (short*)alloc((size_t)8192 * 1024 * 2);
  short* qb = (short*)alloc((size_t)16 * 4096 * 128 * 2);
  short* kb = (short*)alloc((size_t)16 * 4096 * 128 * 2);
  short* vb = (short*)alloc((size_t)16 * 4096 * 128 * 2);
  short* vT = (short*)alloc((size_t)16 * 128 * 4096 * 2);
  short* g = (short*)(base + phase);  // [8192,4096] bf16, reuses xln/q/k/v

  dim3 T256(256);
  transpose_bf16<float><<<dim3(32, 32, 1), T256, 0, stream>>>(wq, wqT, 1024, 1024);
  transpose_bf16<float><<<dim3(32, 32, 1), T256, 0, stream>>>(wk, wkT, 1024, 1024);
  transpose_bf16<float><<<dim3(32, 32, 1), T256, 0, stream>>>(wv, wvT, 1024, 1024);
  transpose_bf16<float><<<dim3(32, 32, 1), T256, 0, stream>>>(wo, woT, 1024, 1024);
  transpose_bf16<float><<<dim3(128, 32, 1), T256, 0, stream>>>(wi, wiT, 1024, 4096);
  transpose_bf16<float><<<dim3(32, 128, 1), T256, 0, stream>>>(wo2, wo2T, 4096, 1024);

  ln_kernel<<<2048, T256, 0, stream>>>(hidden, ln1w, ln1b, xln);

  gemm128<0><<<dim3(8, 64), T256, 0, stream>>>(xln, wqT, bq, nullptr, qb, nullptr, 8192, 1024, 1024);
  gemm128<0><<<dim3(8, 64), T256, 0, stream>>>(xln, wkT, bk, nullptr, kb, nullptr, 8192, 1024, 1024);
  gemm128<0><<<dim3(8, 64), T256, 0, stream>>>(xln, wvT, bv, nullptr, vb, nullptr, 8192, 1024, 1024);

  rope_kernel<<<16384, T256, 0, stream>>>(qb, kb, cosT, sinT);
  transpose_bf16<short><<<dim3(4, 128, 16), T256, 0, stream>>>(vb, vT, 4096, 128);

  kmean_kernel<<<dim3(8, 16), T256, 0, stream>>>(kb, kmeanB);
  gate_kernel<<<256, T256, 0, stream>>>(qb, kmeanB, selm);

  attn_kernel<<<dim3(64, 16), T256, 0, stream>>>(qb, kb, vT, selm, xattn);

  gemm128<1><<<dim3(8, 64), T256, 0, stream>>>(xattn, woT, bo, hidden, nullptr, outF, 8192, 1024, 1024);
  ln_kernel<<<2048, T256, 0, stream>>>(outF, ln2w, ln2b, h2);
  gemm128<2><<<dim3(32, 64), T256, 0, stream>>>(h2, wiT, bi, nullptr, g, nullptr, 8192, 4096, 1024);
  gemm128<3><<<dim3(8, 64), T256, 0, stream>>>(g, wo2T, bo2, nullptr, nullptr, outF, 8192, 1024, 4096);
}

// Round 2
// 948.375 us; speedup vs baseline: 1.6577x; 1.6577x over previous
//
#include <hip/hip_runtime.h>
#include <cstdint>

#define S_LEN 4096
#define NHEAD 8
#define DHEAD 128
#define DMODEL 1024
#define MOBA_TOPK 4

typedef __attribute__((ext_vector_type(8))) short short8;
typedef __attribute__((ext_vector_type(4))) float f32x4;

__device__ inline float bf2f(short s) {
  return __builtin_bit_cast(float, (unsigned)((unsigned short)s) << 16);
}
__device__ inline short f2bf(float f) {
  unsigned u = __builtin_bit_cast(unsigned, f);
  unsigned r = (u + 0x7fffu + ((u >> 16) & 1u)) >> 16;
  return (short)(unsigned short)r;
}
__device__ inline float toF(float v) { return v; }
__device__ inline float toF(short v) { return bf2f(v); }

#define MFMA(a, b, c) __builtin_amdgcn_mfma_f32_16x16x32_bf16(a, b, c, 0, 0, 0)
#define GLOAD_LDS(gsrc, ldst)                                                  \
  __builtin_amdgcn_global_load_lds(                                            \
      (const __attribute__((address_space(1))) void*)(gsrc),                   \
      (__attribute__((address_space(3))) void*)(ldst), 16, 0, 0)

// ---------------------------------------------------------------- transpose
template <typename T>
__global__ __launch_bounds__(256) void transpose_bf16(const T* __restrict__ in,
                                                      short* __restrict__ out,
                                                      int R, int C) {
  __shared__ float tile[32][33];
  size_t bo = (size_t)blockIdx.z * R * C;
  int c0 = blockIdx.x * 32, r0 = blockIdx.y * 32;
  int tx = threadIdx.x & 31, ty = threadIdx.x >> 5;
#pragma unroll
  for (int i = 0; i < 32; i += 8)
    tile[ty + i][tx] = toF(in[bo + (size_t)(r0 + ty + i) * C + c0 + tx]);
  __syncthreads();
#pragma unroll
  for (int i = 0; i < 32; i += 8)
    out[bo + (size_t)(c0 + ty + i) * R + r0 + tx] = f2bf(tile[tx][ty + i]);
}

// ---------------------------------------------------------------- layernorm
__global__ __launch_bounds__(256) void ln_kernel(const float* __restrict__ x,
                                                 const float* __restrict__ w,
                                                 const float* __restrict__ b,
                                                 short* __restrict__ out) {
  int row = blockIdx.x * 4 + (threadIdx.x >> 6);
  int lane = threadIdx.x & 63;
  const float* xr = x + (size_t)row * DMODEL + lane * 16;
  f32x4 v[4];
  float sum = 0.f, sq = 0.f;
#pragma unroll
  for (int i = 0; i < 4; ++i) {
    v[i] = *(const f32x4*)(xr + i * 4);
#pragma unroll
    for (int j = 0; j < 4; ++j) {
      sum += v[i][j];
      sq += v[i][j] * v[i][j];
    }
  }
#pragma unroll
  for (int d = 1; d < 64; d <<= 1) {
    sum += __shfl_xor(sum, d, 64);
    sq += __shfl_xor(sq, d, 64);
  }
  float mu = sum * (1.f / DMODEL);
  float var = sq * (1.f / DMODEL) - mu * mu;
  float rstd = rsqrtf(var + 1e-5f);
  short* orow = out + (size_t)row * DMODEL;
#pragma unroll
  for (int i = 0; i < 4; ++i)
#pragma unroll
    for (int j = 0; j < 4; ++j) {
      int c = lane * 16 + i * 4 + j;
      orow[c] = f2bf((v[i][j] - mu) * rstd * w[c] + b[c]);
    }
}

// ---------------------------------------------------------------- GEMM
template <int MODE>
__global__ __launch_bounds__(256) void gemm128(const short* __restrict__ A,
                                               const short* __restrict__ BT,
                                               const float* __restrict__ bias,
                                               const float* __restrict__ residF,
                                               short* __restrict__ outB,
                                               float* outF, int M, int N,
                                               int K) {
  __shared__ alignas(16) short As[4096];
  __shared__ alignas(16) short Bs[4096];
  const int t = threadIdx.x;
  const int lane = t & 63, w = t >> 6;
  const int wm = w >> 1, wn = w & 1;
  const int m0 = blockIdx.y * 128, n0 = blockIdx.x * 128;

  const f32x4 fz = {0.f, 0.f, 0.f, 0.f};
  f32x4 acc[4][4];
#pragma unroll
  for (int i = 0; i < 4; ++i)
#pragma unroll
    for (int j = 0; j < 4; ++j) acc[i][j] = fz;

  const int sm = ((t >> 6) << 4) + (t & 15);
  const int sk = ((t >> 4) & 3) << 3;
  const short* gA0 = A + (size_t)(m0 + sm) * K + sk;
  const short* gA1 = A + (size_t)(m0 + 64 + sm) * K + sk;
  const short* gB0 = BT + (size_t)(n0 + sm) * K + sk;
  const short* gB1 = BT + (size_t)(n0 + 64 + sm) * K + sk;

  for (int k0 = 0; k0 < K; k0 += 32) {
    GLOAD_LDS(gA0 + k0, As + t * 8);
    GLOAD_LDS(gA1 + k0, As + 2048 + t * 8);
    GLOAD_LDS(gB0 + k0, Bs + t * 8);
    GLOAD_LDS(gB1 + k0, Bs + 2048 + t * 8);
    __syncthreads();
    short8 af[4], bf[4];
#pragma unroll
    for (int mi = 0; mi < 4; ++mi)
      af[mi] = *(const short8*)(As + ((wm * 4 + mi) << 9) + lane * 8);
#pragma unroll
    for (int ni = 0; ni < 4; ++ni)
      bf[ni] = *(const short8*)(Bs + ((wn * 4 + ni) << 9) + lane * 8);
#pragma unroll
    for (int mi = 0; mi < 4; ++mi)
#pragma unroll
      for (int ni = 0; ni < 4; ++ni)
        acc[mi][ni] = MFMA(af[mi], bf[ni], acc[mi][ni]);
    __syncthreads();
  }

  const int er = lane >> 4, ec = lane & 15;
#pragma unroll
  for (int mi = 0; mi < 4; ++mi) {
#pragma unroll
    for (int ni = 0; ni < 4; ++ni) {
      int col = n0 + wn * 64 + ni * 16 + ec;
      float bs = bias[col];
#pragma unroll
      for (int r = 0; r < 4; ++r) {
        int row = m0 + wm * 64 + mi * 16 + er * 4 + r;
        float v = acc[mi][ni][r] + bs;
        size_t idx = (size_t)row * N + col;
        if (MODE == 0) {
          int b = row >> 12, s = row & 4095;
          int h = col >> 7, dh = col & 127;
          outB[((size_t)((b * NHEAD + h) * S_LEN + s)) * DHEAD + dh] = f2bf(v);
        } else if (MODE == 1) {
          v += residF[idx];
          outF[idx] = v;
        } else if (MODE == 2) {
          float gl = 0.5f * v * (1.f + erff(v * 0.70710678118654752f));
          outB[idx] = f2bf(gl);
        } else {
          v += outF[idx];
          outF[idx] = v;
        }
      }
    }
  }
}

// ---------------------------------------------------------------- RoPE
__global__ __launch_bounds__(256) void rope_kernel(short* __restrict__ q,
                                                   short* __restrict__ k,
                                                   const float* __restrict__ cosT,
                                                   const float* __restrict__ sinT) {
  int row = blockIdx.x * 4 + (threadIdx.x >> 6);
  int lane = threadIdx.x & 63;
  int s = row & (S_LEN - 1);
  float c1 = cosT[s * DHEAD + lane], s1 = sinT[s * DHEAD + lane];
  float c2 = cosT[s * DHEAD + 64 + lane], s2 = sinT[s * DHEAD + 64 + lane];
  size_t base = (size_t)row * DHEAD;
  float a = bf2f(q[base + lane]), bb = bf2f(q[base + 64 + lane]);
  q[base + lane] = f2bf(a * c1 - bb * s1);
  q[base + 64 + lane] = f2bf(bb * c2 + a * s2);
  a = bf2f(k[base + lane]);
  bb = bf2f(k[base + 64 + lane]);
  k[base + lane] = f2bf(a * c1 - bb * s1);
  k[base + 64 + lane] = f2bf(bb * c2 + a * s2);
}

// ---------------------------------------------------------------- kmean
__global__ __launch_bounds__(256) void kmean_kernel(const short* __restrict__ K,
                                                    float* __restrict__ kmean) {
  int n = blockIdx.x, bh = blockIdx.y;
  int t = threadIdx.x;
  int d = t & 127, half = t >> 7;
  const short* base = K + ((size_t)bh * S_LEN + n * 512 + half * 256) * DHEAD + d;
  float s = 0.f;
  for (int i = 0; i < 256; ++i) s += bf2f(base[(size_t)i * DHEAD]);
  __shared__ float red[256];
  red[t] = s;
  __syncthreads();
  if (t < 128)
    kmean[((size_t)bh * 8 + n) * DHEAD + d] = (red[t] + red[t + 128]) * (1.f / 512.f);
}

// ---------------------------------------------------------------- gate / topk
__global__ __launch_bounds__(256) void gate_kernel(const short* __restrict__ Q,
                                                   const float* __restrict__ kmean,
                                                   unsigned* __restrict__ selmask) {
  int bh = blockIdx.x >> 4;
  int s = ((blockIdx.x & 15) << 8) + threadIdx.x;
  __shared__ float km[8 * DHEAD];
  for (int i = threadIdx.x; i < 8 * DHEAD; i += 256)
    km[i] = kmean[(size_t)bh * 8 * DHEAD + i];
  __syncthreads();
  const short* qrow = Q + ((size_t)bh * S_LEN + s) * DHEAD;
  float g[8] = {0, 0, 0, 0, 0, 0, 0, 0};
  for (int c = 0; c < 16; ++c) {
    short8 qv = *(const short8*)(qrow + c * 8);
    float qf[8];
#pragma unroll
    for (int j = 0; j < 8; ++j) qf[j] = bf2f(qv[j]);
#pragma unroll
    for (int n = 0; n < 8; ++n) {
      float a = 0.f;
#pragma unroll
      for (int j = 0; j < 8; ++j) a += qf[j] * km[n * DHEAD + c * 8 + j];
      g[n] += a;
    }
  }
  int own = s >> 9;
  int nvis = own + 1;
  int kcnt = nvis < MOBA_TOPK ? nvis : MOBA_TOPK;
  unsigned used = 0;
  for (int it = 0; it < kcnt; ++it) {
    float best = -1e38f;
    int bi = 0;
    for (int n = 0; n < nvis; ++n)
      if (!((used >> n) & 1) && g[n] > best) {
        best = g[n];
        bi = n;
      }
    used |= 1u << bi;
  }
  selmask[(size_t)bh * S_LEN + s] = used | (1u << own);
}

// ---------------------------------------------------------------- attention
// 8 waves x 16 q = 128 queries/block. KVBLK=64 staged in LDS (K dbuf,
// VT single), swizzled via pre-swizzled global source. Counted vmcnt
// pipeline with raw s_barrier.
__global__ __launch_bounds__(512, 4) void attn_kernel(
    const short* __restrict__ Q, const short* __restrict__ K,
    const short* __restrict__ VT, const unsigned* __restrict__ selmask,
    short* __restrict__ out) {
  const int qt = blockIdx.x, bh = blockIdx.y;
  const int b = bh >> 3, h = bh & 7;
  const int q0t = qt << 7;
  const int t = threadIdx.x, lane = t & 63, w = t >> 6;
  const int er = lane >> 4, ec = lane & 15;

  __shared__ alignas(16) short kbuf[2][8192];   // 2 x 64 keys x 128 dh
  __shared__ alignas(16) short vbuf[8192];      // 128 dh x 64 keys
  __shared__ alignas(16) short plds[8][1152];   // per wave 16 x 72
  __shared__ unsigned selS[128];
  __shared__ unsigned umS[2];
  __shared__ int kbsS[66];

  if (t < 128) selS[t] = selmask[(size_t)bh * S_LEN + q0t + t];
  __syncthreads();
  if (w < 2) {
    unsigned v = selS[w * 64 + lane];
#pragma unroll
    for (int d = 1; d < 64; d <<= 1) v |= __shfl_xor(v, d, 64);
    if (lane == 0) umS[w] = v;
  }
  __syncthreads();
  if (t == 0) {
    unsigned um = umS[0] | umS[1];
    int qmax = q0t + 127;
    int maxb = qmax >> 9;
    int n = 0;
    for (int kb = 0; kb <= maxb; ++kb)
      if ((um >> kb) & 1) {
        int subs = (kb == maxb) ? (((qmax - (kb << 9)) >> 6) + 1) : 8;
        for (int s2 = 0; s2 < subs; ++s2) kbsS[n++] = (kb << 9) + (s2 << 6);
      }
    kbsS[64] = n;
  }
  __syncthreads();
  const int nIter = kbsS[64];

  const size_t sbh = (size_t)bh * S_LEN * DHEAD;
  const short* Kg = K + sbh;
  const short* Vg = VT + (size_t)bh * DHEAD * S_LEN;

  // K stage: lds [key][128dh] swizzled byte ^= (key&7)<<4, via source preswz
  auto kstage = [&](short* dst, int key0) {
#pragma unroll
    for (int rnd = 0; rnd < 2; ++rnd) {
      int p = (t + rnd * 512) << 4;
      int key = p >> 8;
      int lin = p ^ ((key & 7) << 4);
      GLOAD_LDS(Kg + (size_t)(key0 + key) * DHEAD + ((lin & 255) >> 1),
                dst + (p >> 1));
    }
  };
  // VT stage: lds [dh][64keys] swizzled byte ^= (dh&7)<<4
  auto vstage = [&](int key0) {
#pragma unroll
    for (int rnd = 0; rnd < 2; ++rnd) {
      int p = (t + rnd * 512) << 4;
      int dh = p >> 7;
      int lin = p ^ ((dh & 7) << 4);
      GLOAD_LDS(Vg + (size_t)dh * S_LEN + key0 + ((lin & 127) >> 1),
                vbuf + (p >> 1));
    }
  };

  const int q0w = q0t + w * 16;
  short8 qf[4];
#pragma unroll
  for (int ks = 0; ks < 4; ++ks)
    qf[ks] = *(const short8*)(Q + sbh + (size_t)(q0w + ec) * DHEAD + ks * 32 + er * 8);

  unsigned selw[4];
  int qq[4];
#pragma unroll
  for (int r = 0; r < 4; ++r) {
    selw[r] = selS[w * 16 + er * 4 + r];
    qq[r] = q0w + er * 4 + r;
  }

  const f32x4 fz = {0.f, 0.f, 0.f, 0.f};
  f32x4 oacc[8];
#pragma unroll
  for (int n = 0; n < 8; ++n) oacc[n] = fz;
  float mrow[4] = {-1e30f, -1e30f, -1e30f, -1e30f};
  float lrow[4] = {0.f, 0.f, 0.f, 0.f};
  const float scale = 0.088388347648318447f;
  short* pl = &plds[w][0];

  kstage(&kbuf[0][0], kbsS[0]);
  int cur = 0;
  for (int it = 0; it < nIter; ++it) {
    const int key0 = kbsS[it];
    const int kb = key0 >> 9;
    const int key0n = kbsS[(it + 1 < nIter) ? it + 1 : it];
    vstage(key0);
    kstage(&kbuf[cur ^ 1][0], key0n);
    asm volatile("s_waitcnt vmcnt(4)" ::: "memory");
    __builtin_amdgcn_sched_barrier(0);
    __builtin_amdgcn_s_barrier();
    __builtin_amdgcn_sched_barrier(0);

    // ---- QK^T over 64 keys
    const short* kl = &kbuf[cur][0];
    f32x4 sc[4];
#pragma unroll
    for (int kh = 0; kh < 4; ++kh) {
      short8 kf[4];
#pragma unroll
      for (int ks = 0; ks < 4; ++ks) {
        int slot = ((ks << 2) + er) ^ (ec & 7);
        kf[ks] = *(const short8*)(kl + (((kh << 4) + ec) << 7) + (slot << 3));
      }
      f32x4 a = fz;
#pragma unroll
      for (int ks = 0; ks < 4; ++ks) a = MFMA(qf[ks], kf[ks], a);
      sc[kh] = a;
    }

    // ---- online softmax over 64 keys
    float corr[4];
#pragma unroll
    for (int r = 0; r < 4; ++r) {
      const bool sb = (selw[r] >> kb) & 1;
      const int kqoff = qq[r] - key0 - ec;  // kh*16 <= kqoff => visible
      const bool ok0 = sb && (0 <= kqoff);
      const bool ok1 = sb && (16 <= kqoff);
      const bool ok2 = sb && (32 <= kqoff);
      const bool ok3 = sb && (48 <= kqoff);
      float s0 = sc[0][r] * scale, s1 = sc[1][r] * scale;
      float s2 = sc[2][r] * scale, s3 = sc[3][r] * scale;
      float m0 = ok0 ? s0 : -1e30f, m1 = ok1 ? s1 : -1e30f;
      float m2 = ok2 ? s2 : -1e30f, m3 = ok3 ? s3 : -1e30f;
      float mx = fmaxf(fmaxf(m0, m1), fmaxf(m2, m3));
#pragma unroll
      for (int d = 1; d < 16; d <<= 1) mx = fmaxf(mx, __shfl_xor(mx, d, 64));
      const float mnew = fmaxf(mrow[r], mx);
      const float c = __expf(mrow[r] - mnew);
      const float e0 = ok0 ? __expf(s0 - mnew) : 0.f;
      const float e1 = ok1 ? __expf(s1 - mnew) : 0.f;
      const float e2 = ok2 ? __expf(s2 - mnew) : 0.f;
      const float e3 = ok3 ? __expf(s3 - mnew) : 0.f;
      float rs = e0 + e1 + e2 + e3;
#pragma unroll
      for (int d = 1; d < 16; d <<= 1) rs += __shfl_xor(rs, d, 64);
      lrow[r] = lrow[r] * c + rs;
      mrow[r] = mnew;
      corr[r] = c;
      const int prow = (er * 4 + r) * 72;
      pl[prow + ec] = f2bf(e0);
      pl[prow + 16 + ec] = f2bf(e1);
      pl[prow + 32 + ec] = f2bf(e2);
      pl[prow + 48 + ec] = f2bf(e3);
    }
    asm volatile("s_waitcnt lgkmcnt(0)" ::: "memory");
    __builtin_amdgcn_sched_barrier(0);
    const short8 pa0 = *(const short8*)(pl + ec * 72 + er * 8);
    const short8 pa1 = *(const short8*)(pl + ec * 72 + 32 + er * 8);

#pragma unroll
    for (int n = 0; n < 8; ++n)
#pragma unroll
      for (int r = 0; r < 4; ++r) oacc[n][r] *= corr[r];

    asm volatile("s_waitcnt vmcnt(2)" ::: "memory");
    __builtin_amdgcn_sched_barrier(0);
    __builtin_amdgcn_s_barrier();
    __builtin_amdgcn_sched_barrier(0);

    // ---- PV over 64 keys
#pragma unroll
    for (int kc = 0; kc < 2; ++kc) {
      const short8 pa = kc ? pa1 : pa0;
#pragma unroll
      for (int n = 0; n < 8; ++n) {
        int slot = ((kc << 2) + er) ^ (ec & 7);
        short8 vf = *(const short8*)(vbuf + (((n << 4) + ec) << 6) + (slot << 3));
        oacc[n] = MFMA(pa, vf, oacc[n]);
      }
    }
    __builtin_amdgcn_sched_barrier(0);
    __builtin_amdgcn_s_barrier();
    __builtin_amdgcn_sched_barrier(0);
    cur ^= 1;
  }

#pragma unroll
  for (int n = 0; n < 8; ++n) {
#pragma unroll
    for (int r = 0; r < 4; ++r) {
      float v = oacc[n][r] / lrow[r];
      out[((size_t)(b * S_LEN + qq[r])) * DMODEL + h * DHEAD + n * 16 + ec] = f2bf(v);
    }
  }
}

// ---------------------------------------------------------------- launcher
extern "C" void kernel_launch(void* const* d_in, const int* in_sizes, int n_in,
                              void* d_out, int out_size, void* d_ws,
                              size_t ws_size, hipStream_t stream) {
  (void)in_sizes; (void)n_in; (void)out_size; (void)ws_size;
  const float* hidden = (const float*)d_in[0];
  const float* ln1w = (const float*)d_in[1];
  const float* ln1b = (const float*)d_in[2];
  const float* wq = (const float*)d_in[3];
  const float* bq = (const float*)d_in[4];
  const float* wk = (const float*)d_in[5];
  const float* bk = (const float*)d_in[6];
  const float* wv = (const float*)d_in[7];
  const float* bv = (const float*)d_in[8];
  const float* wo = (const float*)d_in[9];
  const float* bo = (const float*)d_in[10];
  const float* ln2w = (const float*)d_in[11];
  const float* ln2b = (const float*)d_in[12];
  const float* wi = (const float*)d_in[13];
  const float* bi = (const float*)d_in[14];
  const float* wo2 = (const float*)d_in[15];
  const float* bo2 = (const float*)d_in[16];
  const float* cosT = (const float*)d_in[17];
  const float* sinT = (const float*)d_in[18];
  float* outF = (float*)d_out;

  char* base = (char*)d_ws;
  size_t off = 0;
  auto alloc = [&](size_t bytes) {
    char* p = base + off;
    off = (off + bytes + 255) & ~(size_t)255;
    return p;
  };
  short* wqT = (short*)alloc((size_t)1024 * 1024 * 2);
  short* wkT = (short*)alloc((size_t)1024 * 1024 * 2);
  short* wvT = (short*)alloc((size_t)1024 * 1024 * 2);
  short* woT = (short*)alloc((size_t)1024 * 1024 * 2);
  short* wiT = (short*)alloc((size_t)4096 * 1024 * 2);
  short* wo2T = (short*)alloc((size_t)1024 * 4096 * 2);
  float* kmeanB = (float*)alloc((size_t)16 * 8 * 128 * 4);
  unsigned* selm = (unsigned*)alloc((size_t)16 * 4096 * 4);
  short* xattn = (short*)alloc((size_t)8192 * 1024 * 2);
  short* h2 = (short*)alloc((size_t)8192 * 1024 * 2);
  size_t phase = off;
  short* xln = (short*)alloc((size_t)8192 * 1024 * 2);
  short* qb = (short*)alloc((size_t)16 * 4096 * 128 * 2);
  short* kb = (short*)alloc((size_t)16 * 4096 * 128 * 2);
  short* vb = (short*)alloc((size_t)16 * 4096 * 128 * 2);
  short* vT = (short*)alloc((size_t)16 * 128 * 4096 * 2);
  short* g = (short*)(base + phase);

  dim3 T256(256);
  transpose_bf16<float><<<dim3(32, 32, 1), T256, 0, stream>>>(wq, wqT, 1024, 1024);
  transpose_bf16<float><<<dim3(32, 32, 1), T256, 0, stream>>>(wk, wkT, 1024, 1024);
  transpose_bf16<float><<<dim3(32, 32, 1), T256, 0, stream>>>(wv, wvT, 1024, 1024);
  transpose_bf16<float><<<dim3(32, 32, 1), T256, 0, stream>>>(wo, woT, 1024, 1024);
  transpose_bf16<float><<<dim3(128, 32, 1), T256, 0, stream>>>(wi, wiT, 1024, 4096);
  transpose_bf16<float><<<dim3(32, 128, 1), T256, 0, stream>>>(wo2, wo2T, 4096, 1024);

  ln_kernel<<<2048, T256, 0, stream>>>(hidden, ln1w, ln1b, xln);

  gemm128<0><<<dim3(8, 64), T256, 0, stream>>>(xln, wqT, bq, nullptr, qb, nullptr, 8192, 1024, 1024);
  gemm128<0><<<dim3(8, 64), T256, 0, stream>>>(xln, wkT, bk, nullptr, kb, nullptr, 8192, 1024, 1024);
  gemm128<0><<<dim3(8, 64), T256, 0, stream>>>(xln, wvT, bv, nullptr, vb, nullptr, 8192, 1024, 1024);

  rope_kernel<<<16384, T256, 0, stream>>>(qb, kb, cosT, sinT);
  transpose_bf16<short><<<dim3(4, 128, 16), T256, 0, stream>>>(vb, vT, 4096, 128);

  kmean_kernel<<<dim3(8, 16), T256, 0, stream>>>(kb, kmeanB);
  gate_kernel<<<256, T256, 0, stream>>>(qb, kmeanB, selm);

  attn_kernel<<<dim3(32, 16), dim3(512), 0, stream>>>(qb, kb, vT, selm, xattn);

  gemm128<1><<<dim3(8, 64), T256, 0, stream>>>(xattn, woT, bo, hidden, nullptr, outF, 8192, 1024, 1024);
  ln_kernel<<<2048, T256, 0, stream>>>(outF, ln2w, ln2b, h2);
  gemm128<2><<<dim3(32, 64), T256, 0, stream>>>(h2, wiT, bi, nullptr, g, nullptr, 8192, 4096, 1024);
  gemm128<3><<<dim3(8, 64), T256, 0, stream>>>(g, wo2T, bo2, nullptr, nullptr, outF, 8192, 1024, 4096);
}

// Round 3
// 851.417 us; speedup vs baseline: 1.8465x; 1.1139x over previous
//
#include <hip/hip_runtime.h>
#include <cstdint>

#define S_LEN 4096
#define NHEAD 8
#define DHEAD 128
#define DMODEL 1024
#define MOBA_TOPK 4

typedef __attribute__((ext_vector_type(8))) short short8;
typedef __attribute__((ext_vector_type(4))) float f32x4;

__device__ inline float bf2f(short s) {
  return __builtin_bit_cast(float, (unsigned)((unsigned short)s) << 16);
}
__device__ inline short f2bf(float f) {
  unsigned u = __builtin_bit_cast(unsigned, f);
  unsigned r = (u + 0x7fffu + ((u >> 16) & 1u)) >> 16;
  return (short)(unsigned short)r;
}
__device__ inline float toF(float v) { return v; }
__device__ inline float toF(short v) { return bf2f(v); }

#define MFMA(a, b, c) __builtin_amdgcn_mfma_f32_16x16x32_bf16(a, b, c, 0, 0, 0)
#define GLOAD_LDS(gsrc, ldst)                                                  \
  __builtin_amdgcn_global_load_lds(                                            \
      (const __attribute__((address_space(1))) void*)(gsrc),                   \
      (__attribute__((address_space(3))) void*)(ldst), 16, 0, 0)

// ---------------------------------------------------------------- transpose
template <typename T>
__global__ __launch_bounds__(256) void transpose_bf16(const T* __restrict__ in,
                                                      short* __restrict__ out,
                                                      int R, int C) {
  __shared__ float tile[32][33];
  size_t bo = (size_t)blockIdx.z * R * C;
  int c0 = blockIdx.x * 32, r0 = blockIdx.y * 32;
  int tx = threadIdx.x & 31, ty = threadIdx.x >> 5;
#pragma unroll
  for (int i = 0; i < 32; i += 8)
    tile[ty + i][tx] = toF(in[bo + (size_t)(r0 + ty + i) * C + c0 + tx]);
  __syncthreads();
#pragma unroll
  for (int i = 0; i < 32; i += 8)
    out[bo + (size_t)(c0 + ty + i) * R + r0 + tx] = f2bf(tile[tx][ty + i]);
}

// ---------------------------------------------------------------- bias pack
__global__ __launch_bounds__(256) void pack_bias(const float* __restrict__ bq,
                                                 const float* __restrict__ bk,
                                                 const float* __restrict__ bv,
                                                 float* __restrict__ dst) {
  int i = blockIdx.x * 256 + threadIdx.x;  // 0..3071
  const float* src = (i < 1024) ? bq : (i < 2048) ? bk : bv;
  dst[i] = src[i & 1023];
}

// ---------------------------------------------------------------- layernorm
__global__ __launch_bounds__(256) void ln_kernel(const float* __restrict__ x,
                                                 const float* __restrict__ w,
                                                 const float* __restrict__ b,
                                                 short* __restrict__ out) {
  int row = blockIdx.x * 4 + (threadIdx.x >> 6);
  int lane = threadIdx.x & 63;
  const float* xr = x + (size_t)row * DMODEL + lane * 16;
  f32x4 v[4];
  float sum = 0.f, sq = 0.f;
#pragma unroll
  for (int i = 0; i < 4; ++i) {
    v[i] = *(const f32x4*)(xr + i * 4);
#pragma unroll
    for (int j = 0; j < 4; ++j) {
      sum += v[i][j];
      sq += v[i][j] * v[i][j];
    }
  }
#pragma unroll
  for (int d = 1; d < 64; d <<= 1) {
    sum += __shfl_xor(sum, d, 64);
    sq += __shfl_xor(sq, d, 64);
  }
  float mu = sum * (1.f / DMODEL);
  float var = sq * (1.f / DMODEL) - mu * mu;
  float rstd = rsqrtf(var + 1e-5f);
  short* orow = out + (size_t)row * DMODEL;
#pragma unroll
  for (int i = 0; i < 4; ++i)
#pragma unroll
    for (int j = 0; j < 4; ++j) {
      int c = lane * 16 + i * 4 + j;
      orow[c] = f2bf((v[i][j] - mu) * rstd * w[c] + b[c]);
    }
}

// ---------------------------------------------------------------- GEMM
// MODE 0: scatter bf16 -> [B,H,S,DH]
// MODE 1: fp32 out = acc + bias + residF
// MODE 2: bf16 out = gelu(acc + bias)
// MODE 3: fp32 outF += acc + bias (in place)
// MODE 4: fused QKV scatter: col -> tensor(col>>10), head, dh
template <int MODE>
__global__ __launch_bounds__(256) void gemm128(const short* __restrict__ A,
                                               const short* __restrict__ BT,
                                               const float* __restrict__ bias,
                                               const float* __restrict__ residF,
                                               short* __restrict__ outB,
                                               float* outF, int M, int N,
                                               int K) {
  __shared__ alignas(16) short As[4096];
  __shared__ alignas(16) short Bs[4096];
  const int t = threadIdx.x;
  const int lane = t & 63, w = t >> 6;
  const int wm = w >> 1, wn = w & 1;
  const int m0 = blockIdx.y * 128, n0 = blockIdx.x * 128;

  const f32x4 fz = {0.f, 0.f, 0.f, 0.f};
  f32x4 acc[4][4];
#pragma unroll
  for (int i = 0; i < 4; ++i)
#pragma unroll
    for (int j = 0; j < 4; ++j) acc[i][j] = fz;

  const int sm = ((t >> 6) << 4) + (t & 15);
  const int sk = ((t >> 4) & 3) << 3;
  const short* gA0 = A + (size_t)(m0 + sm) * K + sk;
  const short* gA1 = A + (size_t)(m0 + 64 + sm) * K + sk;
  const short* gB0 = BT + (size_t)(n0 + sm) * K + sk;
  const short* gB1 = BT + (size_t)(n0 + 64 + sm) * K + sk;

  for (int k0 = 0; k0 < K; k0 += 32) {
    GLOAD_LDS(gA0 + k0, As + t * 8);
    GLOAD_LDS(gA1 + k0, As + 2048 + t * 8);
    GLOAD_LDS(gB0 + k0, Bs + t * 8);
    GLOAD_LDS(gB1 + k0, Bs + 2048 + t * 8);
    __syncthreads();
    short8 af[4], bf[4];
#pragma unroll
    for (int mi = 0; mi < 4; ++mi)
      af[mi] = *(const short8*)(As + ((wm * 4 + mi) << 9) + lane * 8);
#pragma unroll
    for (int ni = 0; ni < 4; ++ni)
      bf[ni] = *(const short8*)(Bs + ((wn * 4 + ni) << 9) + lane * 8);
#pragma unroll
    for (int mi = 0; mi < 4; ++mi)
#pragma unroll
      for (int ni = 0; ni < 4; ++ni)
        acc[mi][ni] = MFMA(af[mi], bf[ni], acc[mi][ni]);
    __syncthreads();
  }

  const int er = lane >> 4, ec = lane & 15;
#pragma unroll
  for (int mi = 0; mi < 4; ++mi) {
#pragma unroll
    for (int ni = 0; ni < 4; ++ni) {
      int col = n0 + wn * 64 + ni * 16 + ec;
      float bs = bias[col];
#pragma unroll
      for (int r = 0; r < 4; ++r) {
        int row = m0 + wm * 64 + mi * 16 + er * 4 + r;
        float v = acc[mi][ni][r] + bs;
        size_t idx = (size_t)row * N + col;
        if (MODE == 0) {
          int b = row >> 12, s = row & 4095;
          int h = col >> 7, dh = col & 127;
          outB[((size_t)((b * NHEAD + h) * S_LEN + s)) * DHEAD + dh] = f2bf(v);
        } else if (MODE == 1) {
          v += residF[idx];
          outF[idx] = v;
        } else if (MODE == 2) {
          float gl = 0.5f * v * (1.f + erff(v * 0.70710678118654752f));
          outB[idx] = f2bf(gl);
        } else if (MODE == 3) {
          v += outF[idx];
          outF[idx] = v;
        } else {
          int b = row >> 12, s = row & 4095;
          int tens = col >> 10, rem = col & 1023;
          int h = rem >> 7, dh = rem & 127;
          outB[(size_t)tens * 8388608 +
               ((size_t)((b * NHEAD + h) * S_LEN + s)) * DHEAD + dh] = f2bf(v);
        }
      }
    }
  }
}

// ---------------------------------------------------------------- RoPE
__global__ __launch_bounds__(256) void rope_kernel(short* __restrict__ q,
                                                   short* __restrict__ k,
                                                   const float* __restrict__ cosT,
                                                   const float* __restrict__ sinT) {
  int row = blockIdx.x * 4 + (threadIdx.x >> 6);
  int lane = threadIdx.x & 63;
  int s = row & (S_LEN - 1);
  float c1 = cosT[s * DHEAD + lane], s1 = sinT[s * DHEAD + lane];
  float c2 = cosT[s * DHEAD + 64 + lane], s2 = sinT[s * DHEAD + 64 + lane];
  size_t base = (size_t)row * DHEAD;
  float a = bf2f(q[base + lane]), bb = bf2f(q[base + 64 + lane]);
  q[base + lane] = f2bf(a * c1 - bb * s1);
  q[base + 64 + lane] = f2bf(bb * c2 + a * s2);
  a = bf2f(k[base + lane]);
  bb = bf2f(k[base + 64 + lane]);
  k[base + lane] = f2bf(a * c1 - bb * s1);
  k[base + 64 + lane] = f2bf(bb * c2 + a * s2);
}

// ---------------------------------------------------------------- kmean
__global__ __launch_bounds__(256) void kmean_kernel(const short* __restrict__ K,
                                                    float* __restrict__ kmean) {
  int n = blockIdx.x, bh = blockIdx.y;
  int t = threadIdx.x;
  int d = t & 127, half = t >> 7;
  const short* base = K + ((size_t)bh * S_LEN + n * 512 + half * 256) * DHEAD + d;
  float s = 0.f;
  for (int i = 0; i < 256; ++i) s += bf2f(base[(size_t)i * DHEAD]);
  __shared__ float red[256];
  red[t] = s;
  __syncthreads();
  if (t < 128)
    kmean[((size_t)bh * 8 + n) * DHEAD + d] = (red[t] + red[t + 128]) * (1.f / 512.f);
}

// ---------------------------------------------------------------- gate / topk
__global__ __launch_bounds__(256) void gate_kernel(const short* __restrict__ Q,
                                                   const float* __restrict__ kmean,
                                                   unsigned* __restrict__ selmask) {
  int bh = blockIdx.x >> 4;
  int s = ((blockIdx.x & 15) << 8) + threadIdx.x;
  __shared__ float km[8 * DHEAD];
  for (int i = threadIdx.x; i < 8 * DHEAD; i += 256)
    km[i] = kmean[(size_t)bh * 8 * DHEAD + i];
  __syncthreads();
  const short* qrow = Q + ((size_t)bh * S_LEN + s) * DHEAD;
  float g[8] = {0, 0, 0, 0, 0, 0, 0, 0};
  for (int c = 0; c < 16; ++c) {
    short8 qv = *(const short8*)(qrow + c * 8);
    float qf[8];
#pragma unroll
    for (int j = 0; j < 8; ++j) qf[j] = bf2f(qv[j]);
#pragma unroll
    for (int n = 0; n < 8; ++n) {
      float a = 0.f;
#pragma unroll
      for (int j = 0; j < 8; ++j) a += qf[j] * km[n * DHEAD + c * 8 + j];
      g[n] += a;
    }
  }
  int own = s >> 9;
  int nvis = own + 1;
  int kcnt = nvis < MOBA_TOPK ? nvis : MOBA_TOPK;
  unsigned used = 0;
  for (int it = 0; it < kcnt; ++it) {
    float best = -1e38f;
    int bi = 0;
    for (int n = 0; n < nvis; ++n)
      if (!((used >> n) & 1) && g[n] > best) {
        best = g[n];
        bi = n;
      }
    used |= 1u << bi;
  }
  selmask[(size_t)bh * S_LEN + s] = used | (1u << own);
}

// ---------------------------------------------------------------- attention
// grid=256 blocks, 8 waves. Each block does units u=blockIdx.x and 511-u
// (qt2 = 31-qt1) so per-block work is constant -> perfect CU load balance.
__global__ __launch_bounds__(512, 2) void attn_kernel(
    const short* __restrict__ Q, const short* __restrict__ K,
    const short* __restrict__ VT, const unsigned* __restrict__ selmask,
    short* __restrict__ out) {
  const int t = threadIdx.x, lane = t & 63, w = t >> 6;
  const int er = lane >> 4, ec = lane & 15;

  __shared__ alignas(16) short kbuf[2][8192];
  __shared__ alignas(16) short vbuf[8192];
  __shared__ alignas(16) short plds[8][1152];
  __shared__ unsigned selS[128];
  __shared__ unsigned umS[2];
  __shared__ int kbsS[66];

  for (int pass = 0; pass < 2; ++pass) {
    const int u = pass ? (511 - (int)blockIdx.x) : (int)blockIdx.x;
    const int qt = u & 31, bh = u >> 5;
    const int b = bh >> 3, h = bh & 7;
    const int q0t = qt << 7;

    if (t < 128) selS[t] = selmask[(size_t)bh * S_LEN + q0t + t];
    __syncthreads();
    if (w < 2) {
      unsigned v = selS[w * 64 + lane];
#pragma unroll
      for (int d = 1; d < 64; d <<= 1) v |= __shfl_xor(v, d, 64);
      if (lane == 0) umS[w] = v;
    }
    __syncthreads();
    if (t == 0) {
      unsigned um = umS[0] | umS[1];
      int qmax = q0t + 127;
      int maxb = qmax >> 9;
      int n = 0;
      for (int kb = 0; kb <= maxb; ++kb)
        if ((um >> kb) & 1) {
          int subs = (kb == maxb) ? (((qmax - (kb << 9)) >> 6) + 1) : 8;
          for (int s2 = 0; s2 < subs; ++s2) kbsS[n++] = (kb << 9) + (s2 << 6);
        }
      kbsS[64] = n;
    }
    __syncthreads();
    const int nIter = kbsS[64];

    const size_t sbh = (size_t)bh * S_LEN * DHEAD;
    const short* Kg = K + sbh;
    const short* Vg = VT + (size_t)bh * DHEAD * S_LEN;

    auto kstage = [&](short* dst, int key0) {
#pragma unroll
      for (int rnd = 0; rnd < 2; ++rnd) {
        int p = (t + rnd * 512) << 4;
        int key = p >> 8;
        int lin = p ^ ((key & 7) << 4);
        GLOAD_LDS(Kg + (size_t)(key0 + key) * DHEAD + ((lin & 255) >> 1),
                  dst + (p >> 1));
      }
    };
    auto vstage = [&](int key0) {
#pragma unroll
      for (int rnd = 0; rnd < 2; ++rnd) {
        int p = (t + rnd * 512) << 4;
        int dh = p >> 7;
        int lin = p ^ ((dh & 7) << 4);
        GLOAD_LDS(Vg + (size_t)dh * S_LEN + key0 + ((lin & 127) >> 1),
                  vbuf + (p >> 1));
      }
    };

    const int q0w = q0t + w * 16;
    short8 qf[4];
#pragma unroll
    for (int ks = 0; ks < 4; ++ks)
      qf[ks] = *(const short8*)(Q + sbh + (size_t)(q0w + ec) * DHEAD + ks * 32 + er * 8);

    unsigned selw[4];
    int qq[4];
#pragma unroll
    for (int r = 0; r < 4; ++r) {
      selw[r] = selS[w * 16 + er * 4 + r];
      qq[r] = q0w + er * 4 + r;
    }

    const f32x4 fz = {0.f, 0.f, 0.f, 0.f};
    f32x4 oacc[8];
#pragma unroll
    for (int n = 0; n < 8; ++n) oacc[n] = fz;
    float mrow[4] = {-1e30f, -1e30f, -1e30f, -1e30f};
    float lrow[4] = {0.f, 0.f, 0.f, 0.f};
    const float scale = 0.088388347648318447f;
    short* pl = &plds[w][0];

    kstage(&kbuf[0][0], kbsS[0]);
    int cur = 0;
    for (int it = 0; it < nIter; ++it) {
      const int key0 = kbsS[it];
      const int kb = key0 >> 9;
      const int key0n = kbsS[(it + 1 < nIter) ? it + 1 : it];
      vstage(key0);
      kstage(&kbuf[cur ^ 1][0], key0n);
      asm volatile("s_waitcnt vmcnt(4)" ::: "memory");
      __builtin_amdgcn_sched_barrier(0);
      __builtin_amdgcn_s_barrier();
      __builtin_amdgcn_sched_barrier(0);

      const short* kl = &kbuf[cur][0];
      f32x4 sc[4];
#pragma unroll
      for (int kh = 0; kh < 4; ++kh) {
        short8 kf[4];
#pragma unroll
        for (int ks = 0; ks < 4; ++ks) {
          int slot = ((ks << 2) + er) ^ (ec & 7);
          kf[ks] = *(const short8*)(kl + (((kh << 4) + ec) << 7) + (slot << 3));
        }
        f32x4 a = fz;
#pragma unroll
        for (int ks = 0; ks < 4; ++ks) a = MFMA(qf[ks], kf[ks], a);
        sc[kh] = a;
      }

      float corr[4];
#pragma unroll
      for (int r = 0; r < 4; ++r) {
        const bool sb = (selw[r] >> kb) & 1;
        const int kqoff = qq[r] - key0 - ec;
        const bool ok0 = sb && (0 <= kqoff);
        const bool ok1 = sb && (16 <= kqoff);
        const bool ok2 = sb && (32 <= kqoff);
        const bool ok3 = sb && (48 <= kqoff);
        float s0 = sc[0][r] * scale, s1 = sc[1][r] * scale;
        float s2 = sc[2][r] * scale, s3 = sc[3][r] * scale;
        float m0 = ok0 ? s0 : -1e30f, m1 = ok1 ? s1 : -1e30f;
        float m2 = ok2 ? s2 : -1e30f, m3 = ok3 ? s3 : -1e30f;
        float mx = fmaxf(fmaxf(m0, m1), fmaxf(m2, m3));
#pragma unroll
        for (int d = 1; d < 16; d <<= 1) mx = fmaxf(mx, __shfl_xor(mx, d, 64));
        const float mnew = fmaxf(mrow[r], mx);
        const float c = __expf(mrow[r] - mnew);
        const float e0 = ok0 ? __expf(s0 - mnew) : 0.f;
        const float e1 = ok1 ? __expf(s1 - mnew) : 0.f;
        const float e2 = ok2 ? __expf(s2 - mnew) : 0.f;
        const float e3 = ok3 ? __expf(s3 - mnew) : 0.f;
        float rs = e0 + e1 + e2 + e3;
#pragma unroll
        for (int d = 1; d < 16; d <<= 1) rs += __shfl_xor(rs, d, 64);
        lrow[r] = lrow[r] * c + rs;
        mrow[r] = mnew;
        corr[r] = c;
        const int prow = (er * 4 + r) * 72;
        pl[prow + ec] = f2bf(e0);
        pl[prow + 16 + ec] = f2bf(e1);
        pl[prow + 32 + ec] = f2bf(e2);
        pl[prow + 48 + ec] = f2bf(e3);
      }
      asm volatile("s_waitcnt lgkmcnt(0)" ::: "memory");
      __builtin_amdgcn_sched_barrier(0);
      const short8 pa0 = *(const short8*)(pl + ec * 72 + er * 8);
      const short8 pa1 = *(const short8*)(pl + ec * 72 + 32 + er * 8);

#pragma unroll
      for (int n = 0; n < 8; ++n)
#pragma unroll
        for (int r = 0; r < 4; ++r) oacc[n][r] *= corr[r];

      asm volatile("s_waitcnt vmcnt(2)" ::: "memory");
      __builtin_amdgcn_sched_barrier(0);
      __builtin_amdgcn_s_barrier();
      __builtin_amdgcn_sched_barrier(0);

#pragma unroll
      for (int kc = 0; kc < 2; ++kc) {
        const short8 pa = kc ? pa1 : pa0;
#pragma unroll
        for (int n = 0; n < 8; ++n) {
          int slot = ((kc << 2) + er) ^ (ec & 7);
          short8 vf = *(const short8*)(vbuf + (((n << 4) + ec) << 6) + (slot << 3));
          oacc[n] = MFMA(pa, vf, oacc[n]);
        }
      }
      __builtin_amdgcn_sched_barrier(0);
      __builtin_amdgcn_s_barrier();
      __builtin_amdgcn_sched_barrier(0);
      cur ^= 1;
    }

#pragma unroll
    for (int n = 0; n < 8; ++n) {
#pragma unroll
      for (int r = 0; r < 4; ++r) {
        float v = oacc[n][r] / lrow[r];
        out[((size_t)(b * S_LEN + qq[r])) * DMODEL + h * DHEAD + n * 16 + ec] = f2bf(v);
      }
    }
    asm volatile("s_waitcnt vmcnt(0)" ::: "memory");
    __syncthreads();
  }
}

// ---------------------------------------------------------------- launcher
extern "C" void kernel_launch(void* const* d_in, const int* in_sizes, int n_in,
                              void* d_out, int out_size, void* d_ws,
                              size_t ws_size, hipStream_t stream) {
  (void)in_sizes; (void)n_in; (void)out_size; (void)ws_size;
  const float* hidden = (const float*)d_in[0];
  const float* ln1w = (const float*)d_in[1];
  const float* ln1b = (const float*)d_in[2];
  const float* wq = (const float*)d_in[3];
  const float* bq = (const float*)d_in[4];
  const float* wk = (const float*)d_in[5];
  const float* bk = (const float*)d_in[6];
  const float* wv = (const float*)d_in[7];
  const float* bv = (const float*)d_in[8];
  const float* wo = (const float*)d_in[9];
  const float* bo = (const float*)d_in[10];
  const float* ln2w = (const float*)d_in[11];
  const float* ln2b = (const float*)d_in[12];
  const float* wi = (const float*)d_in[13];
  const float* bi = (const float*)d_in[14];
  const float* wo2 = (const float*)d_in[15];
  const float* bo2 = (const float*)d_in[16];
  const float* cosT = (const float*)d_in[17];
  const float* sinT = (const float*)d_in[18];
  float* outF = (float*)d_out;

  char* base = (char*)d_ws;
  size_t off = 0;
  auto alloc = [&](size_t bytes) {
    char* p = base + off;
    off = (off + bytes + 255) & ~(size_t)255;
    return p;
  };
  short* wqkvT = (short*)alloc((size_t)3072 * 1024 * 2);
  short* woT = (short*)alloc((size_t)1024 * 1024 * 2);
  short* wiT = (short*)alloc((size_t)4096 * 1024 * 2);
  short* wo2T = (short*)alloc((size_t)1024 * 4096 * 2);
  float* biasC = (float*)alloc((size_t)3072 * 4);
  float* kmeanB = (float*)alloc((size_t)16 * 8 * 128 * 4);
  unsigned* selm = (unsigned*)alloc((size_t)16 * 4096 * 4);
  short* xattn = (short*)alloc((size_t)8192 * 1024 * 2);
  short* h2 = (short*)alloc((size_t)8192 * 1024 * 2);
  size_t phase = off;
  short* xln = (short*)alloc((size_t)8192 * 1024 * 2);
  short* qb = (short*)alloc((size_t)16 * 4096 * 128 * 2);
  short* kb = (short*)alloc((size_t)16 * 4096 * 128 * 2);
  short* vb = (short*)alloc((size_t)16 * 4096 * 128 * 2);
  short* vT = (short*)alloc((size_t)16 * 128 * 4096 * 2);
  short* g = (short*)(base + phase);

  dim3 T256(256);
  transpose_bf16<float><<<dim3(32, 32, 1), T256, 0, stream>>>(wq, wqkvT, 1024, 1024);
  transpose_bf16<float><<<dim3(32, 32, 1), T256, 0, stream>>>(wk, wqkvT + 1048576, 1024, 1024);
  transpose_bf16<float><<<dim3(32, 32, 1), T256, 0, stream>>>(wv, wqkvT + 2097152, 1024, 1024);
  transpose_bf16<float><<<dim3(32, 32, 1), T256, 0, stream>>>(wo, woT, 1024, 1024);
  transpose_bf16<float><<<dim3(128, 32, 1), T256, 0, stream>>>(wi, wiT, 1024, 4096);
  transpose_bf16<float><<<dim3(32, 128, 1), T256, 0, stream>>>(wo2, wo2T, 4096, 1024);
  pack_bias<<<12, T256, 0, stream>>>(bq, bk, bv, biasC);

  ln_kernel<<<2048, T256, 0, stream>>>(hidden, ln1w, ln1b, xln);

  gemm128<4><<<dim3(24, 64), T256, 0, stream>>>(xln, wqkvT, biasC, nullptr, qb, nullptr, 8192, 3072, 1024);

  rope_kernel<<<16384, T256, 0, stream>>>(qb, kb, cosT, sinT);
  transpose_bf16<short><<<dim3(4, 128, 16), T256, 0, stream>>>(vb, vT, 4096, 128);

  kmean_kernel<<<dim3(8, 16), T256, 0, stream>>>(kb, kmeanB);
  gate_kernel<<<256, T256, 0, stream>>>(qb, kmeanB, selm);

  attn_kernel<<<dim3(256), dim3(512), 0, stream>>>(qb, kb, vT, selm, xattn);

  gemm128<1><<<dim3(8, 64), T256, 0, stream>>>(xattn, woT, bo, hidden, nullptr, outF, 8192, 1024, 1024);
  ln_kernel<<<2048, T256, 0, stream>>>(outF, ln2w, ln2b, h2);
  gemm128<2><<<dim3(32, 64), T256, 0, stream>>>(h2, wiT, bi, nullptr, g, nullptr, 8192, 4096, 1024);
  gemm128<3><<<dim3(8, 64), T256, 0, stream>>>(g, wo2T, bo2, nullptr, nullptr, outF, 8192, 1024, 4096);
}

// Round 4
// 726.053 us; speedup vs baseline: 2.1653x; 1.1727x over previous
//
#include <hip/hip_runtime.h>
#include <cstdint>

#define S_LEN 4096
#define NHEAD 8
#define DHEAD 128
#define DMODEL 1024
#define MOBA_TOPK 4

typedef __attribute__((ext_vector_type(8))) short short8;
typedef __attribute__((ext_vector_type(4))) float f32x4;

__device__ inline float bf2f(short s) {
  return __builtin_bit_cast(float, (unsigned)((unsigned short)s) << 16);
}
__device__ inline short f2bf(float f) {
  unsigned u = __builtin_bit_cast(unsigned, f);
  unsigned r = (u + 0x7fffu + ((u >> 16) & 1u)) >> 16;
  return (short)(unsigned short)r;
}
__device__ inline float toF(float v) { return v; }
__device__ inline float toF(short v) { return bf2f(v); }

#define MFMA(a, b, c) __builtin_amdgcn_mfma_f32_16x16x32_bf16(a, b, c, 0, 0, 0)
#define GLOAD_LDS(gsrc, ldst)                                                  \
  __builtin_amdgcn_global_load_lds(                                            \
      (const __attribute__((address_space(1))) void*)(gsrc),                   \
      (__attribute__((address_space(3))) void*)(ldst), 16, 0, 0)

// ---------------------------------------------------------------- transpose
template <typename T>
__global__ __launch_bounds__(256) void transpose_bf16(const T* __restrict__ in,
                                                      short* __restrict__ out,
                                                      int R, int C) {
  __shared__ float tile[32][33];
  size_t bo = (size_t)blockIdx.z * R * C;
  int c0 = blockIdx.x * 32, r0 = blockIdx.y * 32;
  int tx = threadIdx.x & 31, ty = threadIdx.x >> 5;
#pragma unroll
  for (int i = 0; i < 32; i += 8)
    tile[ty + i][tx] = toF(in[bo + (size_t)(r0 + ty + i) * C + c0 + tx]);
  __syncthreads();
#pragma unroll
  for (int i = 0; i < 32; i += 8)
    out[bo + (size_t)(c0 + ty + i) * R + r0 + tx] = f2bf(tile[tx][ty + i]);
}

// ---------------------------------------------------------------- bias pack
__global__ __launch_bounds__(256) void pack_bias(const float* __restrict__ bq,
                                                 const float* __restrict__ bk,
                                                 const float* __restrict__ bv,
                                                 float* __restrict__ dst) {
  int i = blockIdx.x * 256 + threadIdx.x;  // 0..3071
  const float* src = (i < 1024) ? bq : (i < 2048) ? bk : bv;
  dst[i] = src[i & 1023];
}

// ---------------------------------------------------------------- layernorm
__global__ __launch_bounds__(256) void ln_kernel(const float* __restrict__ x,
                                                 const float* __restrict__ w,
                                                 const float* __restrict__ b,
                                                 short* __restrict__ out) {
  int row = blockIdx.x * 4 + (threadIdx.x >> 6);
  int lane = threadIdx.x & 63;
  const float* xr = x + (size_t)row * DMODEL + lane * 16;
  f32x4 v[4];
  float sum = 0.f, sq = 0.f;
#pragma unroll
  for (int i = 0; i < 4; ++i) {
    v[i] = *(const f32x4*)(xr + i * 4);
#pragma unroll
    for (int j = 0; j < 4; ++j) {
      sum += v[i][j];
      sq += v[i][j] * v[i][j];
    }
  }
#pragma unroll
  for (int d = 1; d < 64; d <<= 1) {
    sum += __shfl_xor(sum, d, 64);
    sq += __shfl_xor(sq, d, 64);
  }
  float mu = sum * (1.f / DMODEL);
  float var = sq * (1.f / DMODEL) - mu * mu;
  float rstd = rsqrtf(var + 1e-5f);
  short* orow = out + (size_t)row * DMODEL;
#pragma unroll
  for (int i = 0; i < 4; ++i)
#pragma unroll
    for (int j = 0; j < 4; ++j) {
      int c = lane * 16 + i * 4 + j;
      orow[c] = f2bf((v[i][j] - mu) * rstd * w[c] + b[c]);
    }
}

// ---------------------------------------------------------------- GEMM 256x BN
// C[M,N] = A[M,K](bf16) * BT[N,K]^T (bf16) + bias
// 512 threads, 8 waves = WM (m) x 8/WM (n). BM=256, BK=64, LDS dbuf.
// Staging: global_load_lds w16, linear LDS dest, pre-swizzled global src
// (byte ^= (row&7)<<4). ds_read side applies the same XOR.
// MODE 1: fp32 out = acc + bias + residF
// MODE 2: bf16 out = gelu(acc + bias)
// MODE 3: fp32 outF += acc + bias (in place)
// MODE 4: fused QKV scatter: col -> tensor(col>>10), head, dh
template <int BN, int WM, int MODE>
__global__ __launch_bounds__(512, 2) void gemm256(const short* __restrict__ A,
                                                  const short* __restrict__ BT,
                                                  const float* __restrict__ bias,
                                                  const float* __restrict__ residF,
                                                  short* __restrict__ outB,
                                                  float* outF, int M, int N,
                                                  int K) {
  constexpr int MF = 16 / WM;    // m-frags per wave
  constexpr int NWN = 8 / WM;    // waves along n
  constexpr int RB = BN / 64;    // B stage rounds
  __shared__ alignas(16) short As[2][16384];
  __shared__ alignas(16) short Bs[2][BN * 64];

  const int t = threadIdx.x, lane = t & 63, w = t >> 6;
  const int wm = w / NWN, wn = w % NWN;
  const int m0 = blockIdx.y * 256, n0 = blockIdx.x * BN;
  const int wmBase = wm * (256 / WM);
  const int wnBase = wn * 64;
  const int lr = lane & 15;
  // byte k-offsets for kk=0,1 with swizzle XOR (row&7 == lane&7)
  const int koff0 = ((((lane >> 4) << 4)) ^ ((lane & 7) << 4)) >> 1;
  const int koff1 = ((64 + ((lane >> 4) << 4)) ^ ((lane & 7) << 4)) >> 1;

  const f32x4 fz = {0.f, 0.f, 0.f, 0.f};
  f32x4 acc[MF][4];
#pragma unroll
  for (int i = 0; i < MF; ++i)
#pragma unroll
    for (int j = 0; j < 4; ++j) acc[i][j] = fz;

  auto stageA = [&](short* dst, int k0) {
#pragma unroll
    for (int rd = 0; rd < 4; ++rd) {
      int p = (t << 4) + (rd << 13);
      int row = p >> 7;
      int ks = ((p & 127) ^ ((row & 7) << 4)) >> 1;
      GLOAD_LDS(A + (size_t)(m0 + row) * K + k0 + ks, dst + (p >> 1));
    }
  };
  auto stageB = [&](short* dst, int k0) {
#pragma unroll
    for (int rd = 0; rd < RB; ++rd) {
      int p = (t << 4) + (rd << 13);
      int row = p >> 7;
      int ks = ((p & 127) ^ ((row & 7) << 4)) >> 1;
      GLOAD_LDS(BT + (size_t)(n0 + row) * K + k0 + ks, dst + (p >> 1));
    }
  };

  const int NT = K >> 6;
  stageA(&As[0][0], 0);
  stageB(&Bs[0][0], 0);
  __syncthreads();

  for (int kt = 0; kt < NT; ++kt) {
    const int cur = kt & 1;
    if (kt + 1 < NT) {
      stageA(&As[cur ^ 1][0], (kt + 1) << 6);
      stageB(&Bs[cur ^ 1][0], (kt + 1) << 6);
    }
    __builtin_amdgcn_sched_barrier(0);
    short8 bfr[4][2];
#pragma unroll
    for (int ni = 0; ni < 4; ++ni) {
      int rb = (wnBase + ni * 16 + lr) << 6;
      bfr[ni][0] = *(const short8*)(&Bs[cur][rb + koff0]);
      bfr[ni][1] = *(const short8*)(&Bs[cur][rb + koff1]);
    }
#pragma unroll
    for (int pp = 0; pp < MF / 2; ++pp) {
      const int ra0 = (wmBase + (pp * 2) * 16 + lr) << 6;
      const int ra1 = (wmBase + (pp * 2 + 1) * 16 + lr) << 6;
      short8 a00 = *(const short8*)(&As[cur][ra0 + koff0]);
      short8 a01 = *(const short8*)(&As[cur][ra0 + koff1]);
      short8 a10 = *(const short8*)(&As[cur][ra1 + koff0]);
      short8 a11 = *(const short8*)(&As[cur][ra1 + koff1]);
      __builtin_amdgcn_sched_barrier(0);
      __builtin_amdgcn_s_setprio(1);
#pragma unroll
      for (int ni = 0; ni < 4; ++ni) {
        acc[pp * 2][ni] = MFMA(a00, bfr[ni][0], acc[pp * 2][ni]);
        acc[pp * 2][ni] = MFMA(a01, bfr[ni][1], acc[pp * 2][ni]);
        acc[pp * 2 + 1][ni] = MFMA(a10, bfr[ni][0], acc[pp * 2 + 1][ni]);
        acc[pp * 2 + 1][ni] = MFMA(a11, bfr[ni][1], acc[pp * 2 + 1][ni]);
      }
      __builtin_amdgcn_s_setprio(0);
      __builtin_amdgcn_sched_barrier(0);
    }
    __syncthreads();
  }

  const int er = lane >> 4, ec = lane & 15;
#pragma unroll
  for (int mi = 0; mi < MF; ++mi) {
#pragma unroll
    for (int ni = 0; ni < 4; ++ni) {
      int col = n0 + wnBase + ni * 16 + ec;
      float bs = bias[col];
#pragma unroll
      for (int r = 0; r < 4; ++r) {
        int row = m0 + wmBase + mi * 16 + er * 4 + r;
        float v = acc[mi][ni][r] + bs;
        size_t idx = (size_t)row * N + col;
        if (MODE == 1) {
          v += residF[idx];
          outF[idx] = v;
        } else if (MODE == 2) {
          float gl = 0.5f * v * (1.f + erff(v * 0.70710678118654752f));
          outB[idx] = f2bf(gl);
        } else if (MODE == 3) {
          v += outF[idx];
          outF[idx] = v;
        } else {
          int b = row >> 12, s = row & 4095;
          int tens = col >> 10, rem = col & 1023;
          int h = rem >> 7, dh = rem & 127;
          outB[(size_t)tens * 8388608 +
               ((size_t)((b * NHEAD + h) * S_LEN + s)) * DHEAD + dh] = f2bf(v);
        }
      }
    }
  }
}

// ---------------------------------------------------------------- RoPE
__global__ __launch_bounds__(256) void rope_kernel(short* __restrict__ q,
                                                   short* __restrict__ k,
                                                   const float* __restrict__ cosT,
                                                   const float* __restrict__ sinT) {
  int row = blockIdx.x * 4 + (threadIdx.x >> 6);
  int lane = threadIdx.x & 63;
  int s = row & (S_LEN - 1);
  float c1 = cosT[s * DHEAD + lane], s1 = sinT[s * DHEAD + lane];
  float c2 = cosT[s * DHEAD + 64 + lane], s2 = sinT[s * DHEAD + 64 + lane];
  size_t base = (size_t)row * DHEAD;
  float a = bf2f(q[base + lane]), bb = bf2f(q[base + 64 + lane]);
  q[base + lane] = f2bf(a * c1 - bb * s1);
  q[base + 64 + lane] = f2bf(bb * c2 + a * s2);
  a = bf2f(k[base + lane]);
  bb = bf2f(k[base + 64 + lane]);
  k[base + lane] = f2bf(a * c1 - bb * s1);
  k[base + 64 + lane] = f2bf(bb * c2 + a * s2);
}

// ---------------------------------------------------------------- kmean
__global__ __launch_bounds__(256) void kmean_kernel(const short* __restrict__ K,
                                                    float* __restrict__ kmean) {
  int n = blockIdx.x, bh = blockIdx.y;
  int t = threadIdx.x;
  int d = t & 127, half = t >> 7;
  const short* base = K + ((size_t)bh * S_LEN + n * 512 + half * 256) * DHEAD + d;
  float s = 0.f;
  for (int i = 0; i < 256; ++i) s += bf2f(base[(size_t)i * DHEAD]);
  __shared__ float red[256];
  red[t] = s;
  __syncthreads();
  if (t < 128)
    kmean[((size_t)bh * 8 + n) * DHEAD + d] = (red[t] + red[t + 128]) * (1.f / 512.f);
}

// ---------------------------------------------------------------- gate / topk
__global__ __launch_bounds__(256) void gate_kernel(const short* __restrict__ Q,
                                                   const float* __restrict__ kmean,
                                                   unsigned* __restrict__ selmask) {
  int bh = blockIdx.x >> 4;
  int s = ((blockIdx.x & 15) << 8) + threadIdx.x;
  __shared__ float km[8 * DHEAD];
  for (int i = threadIdx.x; i < 8 * DHEAD; i += 256)
    km[i] = kmean[(size_t)bh * 8 * DHEAD + i];
  __syncthreads();
  const short* qrow = Q + ((size_t)bh * S_LEN + s) * DHEAD;
  float g[8] = {0, 0, 0, 0, 0, 0, 0, 0};
  for (int c = 0; c < 16; ++c) {
    short8 qv = *(const short8*)(qrow + c * 8);
    float qf[8];
#pragma unroll
    for (int j = 0; j < 8; ++j) qf[j] = bf2f(qv[j]);
#pragma unroll
    for (int n = 0; n < 8; ++n) {
      float a = 0.f;
#pragma unroll
      for (int j = 0; j < 8; ++j) a += qf[j] * km[n * DHEAD + c * 8 + j];
      g[n] += a;
    }
  }
  int own = s >> 9;
  int nvis = own + 1;
  int kcnt = nvis < MOBA_TOPK ? nvis : MOBA_TOPK;
  unsigned used = 0;
  for (int it = 0; it < kcnt; ++it) {
    float best = -1e38f;
    int bi = 0;
    for (int n = 0; n < nvis; ++n)
      if (!((used >> n) & 1) && g[n] > best) {
        best = g[n];
        bi = n;
      }
    used |= 1u << bi;
  }
  selmask[(size_t)bh * S_LEN + s] = used | (1u << own);
}

// ---------------------------------------------------------------- attention
// grid=256 blocks, 8 waves. Each block does units u=blockIdx.x and 511-u
// (qt2 = 31-qt1) so per-block work is constant -> perfect CU load balance.
__global__ __launch_bounds__(512, 2) void attn_kernel(
    const short* __restrict__ Q, const short* __restrict__ K,
    const short* __restrict__ VT, const unsigned* __restrict__ selmask,
    short* __restrict__ out) {
  const int t = threadIdx.x, lane = t & 63, w = t >> 6;
  const int er = lane >> 4, ec = lane & 15;

  __shared__ alignas(16) short kbuf[2][8192];
  __shared__ alignas(16) short vbuf[8192];
  __shared__ alignas(16) short plds[8][1152];
  __shared__ unsigned selS[128];
  __shared__ unsigned umS[2];
  __shared__ int kbsS[66];

  for (int pass = 0; pass < 2; ++pass) {
    const int u = pass ? (511 - (int)blockIdx.x) : (int)blockIdx.x;
    const int qt = u & 31, bh = u >> 5;
    const int b = bh >> 3, h = bh & 7;
    const int q0t = qt << 7;

    if (t < 128) selS[t] = selmask[(size_t)bh * S_LEN + q0t + t];
    __syncthreads();
    if (w < 2) {
      unsigned v = selS[w * 64 + lane];
#pragma unroll
      for (int d = 1; d < 64; d <<= 1) v |= __shfl_xor(v, d, 64);
      if (lane == 0) umS[w] = v;
    }
    __syncthreads();
    if (t == 0) {
      unsigned um = umS[0] | umS[1];
      int qmax = q0t + 127;
      int maxb = qmax >> 9;
      int n = 0;
      for (int kb = 0; kb <= maxb; ++kb)
        if ((um >> kb) & 1) {
          int subs = (kb == maxb) ? (((qmax - (kb << 9)) >> 6) + 1) : 8;
          for (int s2 = 0; s2 < subs; ++s2) kbsS[n++] = (kb << 9) + (s2 << 6);
        }
      kbsS[64] = n;
    }
    __syncthreads();
    const int nIter = kbsS[64];

    const size_t sbh = (size_t)bh * S_LEN * DHEAD;
    const short* Kg = K + sbh;
    const short* Vg = VT + (size_t)bh * DHEAD * S_LEN;

    auto kstage = [&](short* dst, int key0) {
#pragma unroll
      for (int rnd = 0; rnd < 2; ++rnd) {
        int p = (t + rnd * 512) << 4;
        int key = p >> 8;
        int lin = p ^ ((key & 7) << 4);
        GLOAD_LDS(Kg + (size_t)(key0 + key) * DHEAD + ((lin & 255) >> 1),
                  dst + (p >> 1));
      }
    };
    auto vstage = [&](int key0) {
#pragma unroll
      for (int rnd = 0; rnd < 2; ++rnd) {
        int p = (t + rnd * 512) << 4;
        int dh = p >> 7;
        int lin = p ^ ((dh & 7) << 4);
        GLOAD_LDS(Vg + (size_t)dh * S_LEN + key0 + ((lin & 127) >> 1),
                  vbuf + (p >> 1));
      }
    };

    const int q0w = q0t + w * 16;
    short8 qf[4];
#pragma unroll
    for (int ks = 0; ks < 4; ++ks)
      qf[ks] = *(const short8*)(Q + sbh + (size_t)(q0w + ec) * DHEAD + ks * 32 + er * 8);

    unsigned selw[4];
    int qq[4];
#pragma unroll
    for (int r = 0; r < 4; ++r) {
      selw[r] = selS[w * 16 + er * 4 + r];
      qq[r] = q0w + er * 4 + r;
    }

    const f32x4 fz = {0.f, 0.f, 0.f, 0.f};
    f32x4 oacc[8];
#pragma unroll
    for (int n = 0; n < 8; ++n) oacc[n] = fz;
    float mrow[4] = {-1e30f, -1e30f, -1e30f, -1e30f};
    float lrow[4] = {0.f, 0.f, 0.f, 0.f};
    const float scale = 0.088388347648318447f;
    short* pl = &plds[w][0];

    kstage(&kbuf[0][0], kbsS[0]);
    int cur = 0;
    for (int it = 0; it < nIter; ++it) {
      const int key0 = kbsS[it];
      const int kb = key0 >> 9;
      const int key0n = kbsS[(it + 1 < nIter) ? it + 1 : it];
      vstage(key0);
      kstage(&kbuf[cur ^ 1][0], key0n);
      asm volatile("s_waitcnt vmcnt(4)" ::: "memory");
      __builtin_amdgcn_sched_barrier(0);
      __builtin_amdgcn_s_barrier();
      __builtin_amdgcn_sched_barrier(0);

      const short* kl = &kbuf[cur][0];
      f32x4 sc[4];
#pragma unroll
      for (int kh = 0; kh < 4; ++kh) {
        short8 kf[4];
#pragma unroll
        for (int ks = 0; ks < 4; ++ks) {
          int slot = ((ks << 2) + er) ^ (ec & 7);
          kf[ks] = *(const short8*)(kl + (((kh << 4) + ec) << 7) + (slot << 3));
        }
        f32x4 a = fz;
#pragma unroll
        for (int ks = 0; ks < 4; ++ks) a = MFMA(qf[ks], kf[ks], a);
        sc[kh] = a;
      }

      float corr[4];
#pragma unroll
      for (int r = 0; r < 4; ++r) {
        const bool sb = (selw[r] >> kb) & 1;
        const int kqoff = qq[r] - key0 - ec;
        const bool ok0 = sb && (0 <= kqoff);
        const bool ok1 = sb && (16 <= kqoff);
        const bool ok2 = sb && (32 <= kqoff);
        const bool ok3 = sb && (48 <= kqoff);
        float s0 = sc[0][r] * scale, s1 = sc[1][r] * scale;
        float s2 = sc[2][r] * scale, s3 = sc[3][r] * scale;
        float m0 = ok0 ? s0 : -1e30f, m1 = ok1 ? s1 : -1e30f;
        float m2 = ok2 ? s2 : -1e30f, m3 = ok3 ? s3 : -1e30f;
        float mx = fmaxf(fmaxf(m0, m1), fmaxf(m2, m3));
#pragma unroll
        for (int d = 1; d < 16; d <<= 1) mx = fmaxf(mx, __shfl_xor(mx, d, 64));
        const float mnew = fmaxf(mrow[r], mx);
        const float c = __expf(mrow[r] - mnew);
        const float e0 = ok0 ? __expf(s0 - mnew) : 0.f;
        const float e1 = ok1 ? __expf(s1 - mnew) : 0.f;
        const float e2 = ok2 ? __expf(s2 - mnew) : 0.f;
        const float e3 = ok3 ? __expf(s3 - mnew) : 0.f;
        float rs = e0 + e1 + e2 + e3;
#pragma unroll
        for (int d = 1; d < 16; d <<= 1) rs += __shfl_xor(rs, d, 64);
        lrow[r] = lrow[r] * c + rs;
        mrow[r] = mnew;
        corr[r] = c;
        const int prow = (er * 4 + r) * 72;
        pl[prow + ec] = f2bf(e0);
        pl[prow + 16 + ec] = f2bf(e1);
        pl[prow + 32 + ec] = f2bf(e2);
        pl[prow + 48 + ec] = f2bf(e3);
      }
      asm volatile("s_waitcnt lgkmcnt(0)" ::: "memory");
      __builtin_amdgcn_sched_barrier(0);
      const short8 pa0 = *(const short8*)(pl + ec * 72 + er * 8);
      const short8 pa1 = *(const short8*)(pl + ec * 72 + 32 + er * 8);

#pragma unroll
      for (int n = 0; n < 8; ++n)
#pragma unroll
        for (int r = 0; r < 4; ++r) oacc[n][r] *= corr[r];

      asm volatile("s_waitcnt vmcnt(2)" ::: "memory");
      __builtin_amdgcn_sched_barrier(0);
      __builtin_amdgcn_s_barrier();
      __builtin_amdgcn_sched_barrier(0);

#pragma unroll
      for (int kc = 0; kc < 2; ++kc) {
        const short8 pa = kc ? pa1 : pa0;
#pragma unroll
        for (int n = 0; n < 8; ++n) {
          int slot = ((kc << 2) + er) ^ (ec & 7);
          short8 vf = *(const short8*)(vbuf + (((n << 4) + ec) << 6) + (slot << 3));
          oacc[n] = MFMA(pa, vf, oacc[n]);
        }
      }
      __builtin_amdgcn_sched_barrier(0);
      __builtin_amdgcn_s_barrier();
      __builtin_amdgcn_sched_barrier(0);
      cur ^= 1;
    }

#pragma unroll
    for (int n = 0; n < 8; ++n) {
#pragma unroll
      for (int r = 0; r < 4; ++r) {
        float v = oacc[n][r] / lrow[r];
        out[((size_t)(b * S_LEN + qq[r])) * DMODEL + h * DHEAD + n * 16 + ec] = f2bf(v);
      }
    }
    asm volatile("s_waitcnt vmcnt(0)" ::: "memory");
    __syncthreads();
  }
}

// ---------------------------------------------------------------- launcher
extern "C" void kernel_launch(void* const* d_in, const int* in_sizes, int n_in,
                              void* d_out, int out_size, void* d_ws,
                              size_t ws_size, hipStream_t stream) {
  (void)in_sizes; (void)n_in; (void)out_size; (void)ws_size;
  const float* hidden = (const float*)d_in[0];
  const float* ln1w = (const float*)d_in[1];
  const float* ln1b = (const float*)d_in[2];
  const float* wq = (const float*)d_in[3];
  const float* bq = (const float*)d_in[4];
  const float* wk = (const float*)d_in[5];
  const float* bk = (const float*)d_in[6];
  const float* wv = (const float*)d_in[7];
  const float* bv = (const float*)d_in[8];
  const float* wo = (const float*)d_in[9];
  const float* bo = (const float*)d_in[10];
  const float* ln2w = (const float*)d_in[11];
  const float* ln2b = (const float*)d_in[12];
  const float* wi = (const float*)d_in[13];
  const float* bi = (const float*)d_in[14];
  const float* wo2 = (const float*)d_in[15];
  const float* bo2 = (const float*)d_in[16];
  const float* cosT = (const float*)d_in[17];
  const float* sinT = (const float*)d_in[18];
  float* outF = (float*)d_out;

  char* base = (char*)d_ws;
  size_t off = 0;
  auto alloc = [&](size_t bytes) {
    char* p = base + off;
    off = (off + bytes + 255) & ~(size_t)255;
    return p;
  };
  short* wqkvT = (short*)alloc((size_t)3072 * 1024 * 2);
  short* woT = (short*)alloc((size_t)1024 * 1024 * 2);
  short* wiT = (short*)alloc((size_t)4096 * 1024 * 2);
  short* wo2T = (short*)alloc((size_t)1024 * 4096 * 2);
  float* biasC = (float*)alloc((size_t)3072 * 4);
  float* kmeanB = (float*)alloc((size_t)16 * 8 * 128 * 4);
  unsigned* selm = (unsigned*)alloc((size_t)16 * 4096 * 4);
  short* xattn = (short*)alloc((size_t)8192 * 1024 * 2);
  short* h2 = (short*)alloc((size_t)8192 * 1024 * 2);
  size_t phase = off;
  short* xln = (short*)alloc((size_t)8192 * 1024 * 2);
  short* qb = (short*)alloc((size_t)16 * 4096 * 128 * 2);
  short* kb = (short*)alloc((size_t)16 * 4096 * 128 * 2);
  short* vb = (short*)alloc((size_t)16 * 4096 * 128 * 2);
  short* vT = (short*)alloc((size_t)16 * 128 * 4096 * 2);
  short* g = (short*)(base + phase);

  dim3 T256(256);
  dim3 T512(512);
  transpose_bf16<float><<<dim3(32, 32, 1), T256, 0, stream>>>(wq, wqkvT, 1024, 1024);
  transpose_bf16<float><<<dim3(32, 32, 1), T256, 0, stream>>>(wk, wqkvT + 1048576, 1024, 1024);
  transpose_bf16<float><<<dim3(32, 32, 1), T256, 0, stream>>>(wv, wqkvT + 2097152, 1024, 1024);
  transpose_bf16<float><<<dim3(32, 32, 1), T256, 0, stream>>>(wo, woT, 1024, 1024);
  transpose_bf16<float><<<dim3(128, 32, 1), T256, 0, stream>>>(wi, wiT, 1024, 4096);
  transpose_bf16<float><<<dim3(32, 128, 1), T256, 0, stream>>>(wo2, wo2T, 4096, 1024);
  pack_bias<<<12, T256, 0, stream>>>(bq, bk, bv, biasC);

  ln_kernel<<<2048, T256, 0, stream>>>(hidden, ln1w, ln1b, xln);

  gemm256<256, 2, 4><<<dim3(12, 32), T512, 0, stream>>>(xln, wqkvT, biasC, nullptr, qb, nullptr, 8192, 3072, 1024);

  rope_kernel<<<16384, T256, 0, stream>>>(qb, kb, cosT, sinT);
  transpose_bf16<short><<<dim3(4, 128, 16), T256, 0, stream>>>(vb, vT, 4096, 128);

  kmean_kernel<<<dim3(8, 16), T256, 0, stream>>>(kb, kmeanB);
  gate_kernel<<<256, T256, 0, stream>>>(qb, kmeanB, selm);

  attn_kernel<<<dim3(256), T512, 0, stream>>>(qb, kb, vT, selm, xattn);

  gemm256<128, 4, 1><<<dim3(8, 32), T512, 0, stream>>>(xattn, woT, bo, hidden, nullptr, outF, 8192, 1024, 1024);
  ln_kernel<<<2048, T256, 0, stream>>>(outF, ln2w, ln2b, h2);
  gemm256<256, 2, 2><<<dim3(16, 32), T512, 0, stream>>>(h2, wiT, bi, nullptr, g, nullptr, 8192, 4096, 1024);
  gemm256<128, 4, 3><<<dim3(8, 32), T512, 0, stream>>>(g, wo2T, bo2, nullptr, nullptr, outF, 8192, 1024, 4096);
}

// Round 5
// 674.969 us; speedup vs baseline: 2.3292x; 1.0757x over previous
//
#include <hip/hip_runtime.h>
#include <cstdint>

#define S_LEN 4096
#define NHEAD 8
#define DHEAD 128
#define DMODEL 1024
#define MOBA_TOPK 4

typedef __attribute__((ext_vector_type(8))) short short8;
typedef __attribute__((ext_vector_type(4))) float f32x4;

__device__ inline float bf2f(short s) {
  return __builtin_bit_cast(float, (unsigned)((unsigned short)s) << 16);
}
__device__ inline short f2bf(float f) {
  unsigned u = __builtin_bit_cast(unsigned, f);
  unsigned r = (u + 0x7fffu + ((u >> 16) & 1u)) >> 16;
  return (short)(unsigned short)r;
}
__device__ inline float toF(float v) { return v; }
__device__ inline float toF(short v) { return bf2f(v); }

#define MFMA(a, b, c) __builtin_amdgcn_mfma_f32_16x16x32_bf16(a, b, c, 0, 0, 0)
#define GLOAD_LDS(gsrc, ldst)                                                  \
  __builtin_amdgcn_global_load_lds(                                            \
      (const __attribute__((address_space(1))) void*)(gsrc),                   \
      (__attribute__((address_space(3))) void*)(ldst), 16, 0, 0)

// ---------------------------------------------------------------- transpose
template <typename T>
__global__ __launch_bounds__(256) void transpose_bf16(const T* __restrict__ in,
                                                      short* __restrict__ out,
                                                      int R, int C) {
  __shared__ float tile[32][33];
  size_t bo = (size_t)blockIdx.z * R * C;
  int c0 = blockIdx.x * 32, r0 = blockIdx.y * 32;
  int tx = threadIdx.x & 31, ty = threadIdx.x >> 5;
#pragma unroll
  for (int i = 0; i < 32; i += 8)
    tile[ty + i][tx] = toF(in[bo + (size_t)(r0 + ty + i) * C + c0 + tx]);
  __syncthreads();
#pragma unroll
  for (int i = 0; i < 32; i += 8)
    out[bo + (size_t)(c0 + ty + i) * R + r0 + tx] = f2bf(tile[tx][ty + i]);
}

// ---------------------------------------------------------------- bias pack
__global__ __launch_bounds__(256) void pack_bias(const float* __restrict__ bq,
                                                 const float* __restrict__ bk,
                                                 const float* __restrict__ bv,
                                                 float* __restrict__ dst) {
  int i = blockIdx.x * 256 + threadIdx.x;  // 0..3071
  const float* src = (i < 1024) ? bq : (i < 2048) ? bk : bv;
  dst[i] = src[i & 1023];
}

// ---------------------------------------------------------------- layernorm
__global__ __launch_bounds__(256) void ln_kernel(const float* __restrict__ x,
                                                 const float* __restrict__ w,
                                                 const float* __restrict__ b,
                                                 short* __restrict__ out) {
  int row = blockIdx.x * 4 + (threadIdx.x >> 6);
  int lane = threadIdx.x & 63;
  const float* xr = x + (size_t)row * DMODEL + lane * 16;
  f32x4 v[4];
  float sum = 0.f, sq = 0.f;
#pragma unroll
  for (int i = 0; i < 4; ++i) {
    v[i] = *(const f32x4*)(xr + i * 4);
#pragma unroll
    for (int j = 0; j < 4; ++j) {
      sum += v[i][j];
      sq += v[i][j] * v[i][j];
    }
  }
#pragma unroll
  for (int d = 1; d < 64; d <<= 1) {
    sum += __shfl_xor(sum, d, 64);
    sq += __shfl_xor(sq, d, 64);
  }
  float mu = sum * (1.f / DMODEL);
  float var = sq * (1.f / DMODEL) - mu * mu;
  float rstd = rsqrtf(var + 1e-5f);
  short* orow = out + (size_t)row * DMODEL;
#pragma unroll
  for (int i = 0; i < 4; ++i)
#pragma unroll
    for (int j = 0; j < 4; ++j) {
      int c = lane * 16 + i * 4 + j;
      orow[c] = f2bf((v[i][j] - mu) * rstd * w[c] + b[c]);
    }
}

// ---------------------------------------------------------------- GEMM 256x BN
template <int BN, int WM, int MODE>
__global__ __launch_bounds__(512, 2) void gemm256(const short* __restrict__ A,
                                                  const short* __restrict__ BT,
                                                  const float* __restrict__ bias,
                                                  const float* __restrict__ residF,
                                                  short* __restrict__ outB,
                                                  float* outF, int M, int N,
                                                  int K) {
  constexpr int MF = 16 / WM;    // m-frags per wave
  constexpr int NWN = 8 / WM;    // waves along n
  constexpr int RB = BN / 64;    // B stage rounds
  __shared__ alignas(16) short As[2][16384];
  __shared__ alignas(16) short Bs[2][BN * 64];

  const int t = threadIdx.x, lane = t & 63, w = t >> 6;
  const int wm = w / NWN, wn = w % NWN;
  const int m0 = blockIdx.y * 256, n0 = blockIdx.x * BN;
  const int wmBase = wm * (256 / WM);
  const int wnBase = wn * 64;
  const int lr = lane & 15;
  const int koff0 = ((((lane >> 4) << 4)) ^ ((lane & 7) << 4)) >> 1;
  const int koff1 = ((64 + ((lane >> 4) << 4)) ^ ((lane & 7) << 4)) >> 1;

  const f32x4 fz = {0.f, 0.f, 0.f, 0.f};
  f32x4 acc[MF][4];
#pragma unroll
  for (int i = 0; i < MF; ++i)
#pragma unroll
    for (int j = 0; j < 4; ++j) acc[i][j] = fz;

  auto stageA = [&](short* dst, int k0) {
#pragma unroll
    for (int rd = 0; rd < 4; ++rd) {
      int p = (t << 4) + (rd << 13);
      int row = p >> 7;
      int ks = ((p & 127) ^ ((row & 7) << 4)) >> 1;
      GLOAD_LDS(A + (size_t)(m0 + row) * K + k0 + ks, dst + (p >> 1));
    }
  };
  auto stageB = [&](short* dst, int k0) {
#pragma unroll
    for (int rd = 0; rd < RB; ++rd) {
      int p = (t << 4) + (rd << 13);
      int row = p >> 7;
      int ks = ((p & 127) ^ ((row & 7) << 4)) >> 1;
      GLOAD_LDS(BT + (size_t)(n0 + row) * K + k0 + ks, dst + (p >> 1));
    }
  };

  const int NT = K >> 6;
  stageA(&As[0][0], 0);
  stageB(&Bs[0][0], 0);
  __syncthreads();

  for (int kt = 0; kt < NT; ++kt) {
    const int cur = kt & 1;
    if (kt + 1 < NT) {
      stageA(&As[cur ^ 1][0], (kt + 1) << 6);
      stageB(&Bs[cur ^ 1][0], (kt + 1) << 6);
    }
    __builtin_amdgcn_sched_barrier(0);
    short8 bfr[4][2];
#pragma unroll
    for (int ni = 0; ni < 4; ++ni) {
      int rb = (wnBase + ni * 16 + lr) << 6;
      bfr[ni][0] = *(const short8*)(&Bs[cur][rb + koff0]);
      bfr[ni][1] = *(const short8*)(&Bs[cur][rb + koff1]);
    }
#pragma unroll
    for (int pp = 0; pp < MF / 2; ++pp) {
      const int ra0 = (wmBase + (pp * 2) * 16 + lr) << 6;
      const int ra1 = (wmBase + (pp * 2 + 1) * 16 + lr) << 6;
      short8 a00 = *(const short8*)(&As[cur][ra0 + koff0]);
      short8 a01 = *(const short8*)(&As[cur][ra0 + koff1]);
      short8 a10 = *(const short8*)(&As[cur][ra1 + koff0]);
      short8 a11 = *(const short8*)(&As[cur][ra1 + koff1]);
      __builtin_amdgcn_sched_barrier(0);
      __builtin_amdgcn_s_setprio(1);
#pragma unroll
      for (int ni = 0; ni < 4; ++ni) {
        acc[pp * 2][ni] = MFMA(a00, bfr[ni][0], acc[pp * 2][ni]);
        acc[pp * 2][ni] = MFMA(a01, bfr[ni][1], acc[pp * 2][ni]);
        acc[pp * 2 + 1][ni] = MFMA(a10, bfr[ni][0], acc[pp * 2 + 1][ni]);
        acc[pp * 2 + 1][ni] = MFMA(a11, bfr[ni][1], acc[pp * 2 + 1][ni]);
      }
      __builtin_amdgcn_s_setprio(0);
      __builtin_amdgcn_sched_barrier(0);
    }
    __syncthreads();
  }

  const int er = lane >> 4, ec = lane & 15;
#pragma unroll
  for (int mi = 0; mi < MF; ++mi) {
#pragma unroll
    for (int ni = 0; ni < 4; ++ni) {
      int col = n0 + wnBase + ni * 16 + ec;
      float bs = bias[col];
#pragma unroll
      for (int r = 0; r < 4; ++r) {
        int row = m0 + wmBase + mi * 16 + er * 4 + r;
        float v = acc[mi][ni][r] + bs;
        size_t idx = (size_t)row * N + col;
        if (MODE == 1) {
          v += residF[idx];
          outF[idx] = v;
        } else if (MODE == 2) {
          float gl = 0.5f * v * (1.f + erff(v * 0.70710678118654752f));
          outB[idx] = f2bf(gl);
        } else if (MODE == 3) {
          v += outF[idx];
          outF[idx] = v;
        } else {
          int b = row >> 12, s = row & 4095;
          int tens = col >> 10, rem = col & 1023;
          int h = rem >> 7, dh = rem & 127;
          outB[(size_t)tens * 8388608 +
               ((size_t)((b * NHEAD + h) * S_LEN + s)) * DHEAD + dh] = f2bf(v);
        }
      }
    }
  }
}

// ---------------------------------------------------------------- RoPE
__global__ __launch_bounds__(256) void rope_kernel(short* __restrict__ q,
                                                   short* __restrict__ k,
                                                   const float* __restrict__ cosT,
                                                   const float* __restrict__ sinT) {
  int row = blockIdx.x * 4 + (threadIdx.x >> 6);
  int lane = threadIdx.x & 63;
  int s = row & (S_LEN - 1);
  float c1 = cosT[s * DHEAD + lane], s1 = sinT[s * DHEAD + lane];
  float c2 = cosT[s * DHEAD + 64 + lane], s2 = sinT[s * DHEAD + 64 + lane];
  size_t base = (size_t)row * DHEAD;
  float a = bf2f(q[base + lane]), bb = bf2f(q[base + 64 + lane]);
  q[base + lane] = f2bf(a * c1 - bb * s1);
  q[base + 64 + lane] = f2bf(bb * c2 + a * s2);
  a = bf2f(k[base + lane]);
  bb = bf2f(k[base + 64 + lane]);
  k[base + lane] = f2bf(a * c1 - bb * s1);
  k[base + 64 + lane] = f2bf(bb * c2 + a * s2);
}

// ---------------------------------------------------------------- kmean
__global__ __launch_bounds__(256) void kmean_kernel(const short* __restrict__ K,
                                                    float* __restrict__ kmean) {
  int n = blockIdx.x, bh = blockIdx.y;
  int t = threadIdx.x;
  int d = t & 127, half = t >> 7;
  const short* base = K + ((size_t)bh * S_LEN + n * 512 + half * 256) * DHEAD + d;
  float s = 0.f;
  for (int i = 0; i < 256; ++i) s += bf2f(base[(size_t)i * DHEAD]);
  __shared__ float red[256];
  red[t] = s;
  __syncthreads();
  if (t < 128)
    kmean[((size_t)bh * 8 + n) * DHEAD + d] = (red[t] + red[t + 128]) * (1.f / 512.f);
}

// ---------------------------------------------------------------- gate / topk
__global__ __launch_bounds__(256) void gate_kernel(const short* __restrict__ Q,
                                                   const float* __restrict__ kmean,
                                                   unsigned* __restrict__ selmask) {
  int bh = blockIdx.x >> 4;
  int s = ((blockIdx.x & 15) << 8) + threadIdx.x;
  __shared__ float km[8 * DHEAD];
  for (int i = threadIdx.x; i < 8 * DHEAD; i += 256)
    km[i] = kmean[(size_t)bh * 8 * DHEAD + i];
  __syncthreads();
  const short* qrow = Q + ((size_t)bh * S_LEN + s) * DHEAD;
  float g[8] = {0, 0, 0, 0, 0, 0, 0, 0};
  for (int c = 0; c < 16; ++c) {
    short8 qv = *(const short8*)(qrow + c * 8);
    float qf[8];
#pragma unroll
    for (int j = 0; j < 8; ++j) qf[j] = bf2f(qv[j]);
#pragma unroll
    for (int n = 0; n < 8; ++n) {
      float a = 0.f;
#pragma unroll
      for (int j = 0; j < 8; ++j) a += qf[j] * km[n * DHEAD + c * 8 + j];
      g[n] += a;
    }
  }
  int own = s >> 9;
  int nvis = own + 1;
  int kcnt = nvis < MOBA_TOPK ? nvis : MOBA_TOPK;
  unsigned used = 0;
  for (int it = 0; it < kcnt; ++it) {
    float best = -1e38f;
    int bi = 0;
    for (int n = 0; n < nvis; ++n)
      if (!((used >> n) & 1) && g[n] > best) {
        best = g[n];
        bi = n;
      }
    used |= 1u << bi;
  }
  selmask[(size_t)bh * S_LEN + s] = used | (1u << own);
}

// ---------------------------------------------------------------- attention
// grid=256 blocks, 8 waves. Swapped QK^T (rows=keys, cols=queries): each
// lane owns ONE query -> scalar m/l, 2-shuffle reductions, packed P writes,
// defer-max rescale. Per-block work constant (units u and 511-u).
__global__ __launch_bounds__(512, 4) void attn_kernel(
    const short* __restrict__ Q, const short* __restrict__ K,
    const short* __restrict__ VT, const unsigned* __restrict__ selmask,
    short* __restrict__ out) {
  const int t = threadIdx.x, lane = t & 63, w = t >> 6;
  const int er = lane >> 4, ec = lane & 15;
  const int er4 = er << 2;

  __shared__ alignas(16) short kbuf[2][8192];
  __shared__ alignas(16) short vbuf[8192];
  __shared__ alignas(16) short plds[8][1152];
  __shared__ unsigned selS[128];
  __shared__ unsigned umS[2];
  __shared__ int kbsS[66];

  const float C = 0.12751742946f;  // log2(e)/sqrt(128)

  for (int pass = 0; pass < 2; ++pass) {
    const int u = pass ? (511 - (int)blockIdx.x) : (int)blockIdx.x;
    const int qt = u & 31, bh = u >> 5;
    const int b = bh >> 3, h = bh & 7;
    const int q0t = qt << 7;

    if (t < 128) selS[t] = selmask[(size_t)bh * S_LEN + q0t + t];
    __syncthreads();
    if (w < 2) {
      unsigned v = selS[w * 64 + lane];
#pragma unroll
      for (int d = 1; d < 64; d <<= 1) v |= __shfl_xor(v, d, 64);
      if (lane == 0) umS[w] = v;
    }
    __syncthreads();
    if (t == 0) {
      unsigned um = umS[0] | umS[1];
      int qmax = q0t + 127;
      int maxb = qmax >> 9;
      int n = 0;
      for (int kb = 0; kb <= maxb; ++kb)
        if ((um >> kb) & 1) {
          int subs = (kb == maxb) ? (((qmax - (kb << 9)) >> 6) + 1) : 8;
          for (int s2 = 0; s2 < subs; ++s2) kbsS[n++] = (kb << 9) + (s2 << 6);
        }
      kbsS[64] = n;
    }
    __syncthreads();
    const int nIter = kbsS[64];

    const size_t sbh = (size_t)bh * S_LEN * DHEAD;
    const short* Kg = K + sbh;
    const short* Vg = VT + (size_t)bh * DHEAD * S_LEN;

    auto kstage = [&](short* dst, int key0) {
#pragma unroll
      for (int rnd = 0; rnd < 2; ++rnd) {
        int p = (t + rnd * 512) << 4;
        int key = p >> 8;
        int lin = p ^ ((key & 7) << 4);
        GLOAD_LDS(Kg + (size_t)(key0 + key) * DHEAD + ((lin & 255) >> 1),
                  dst + (p >> 1));
      }
    };
    auto vstage = [&](int key0) {
#pragma unroll
      for (int rnd = 0; rnd < 2; ++rnd) {
        int p = (t + rnd * 512) << 4;
        int dh = p >> 7;
        int lin = p ^ ((dh & 7) << 4);
        GLOAD_LDS(Vg + (size_t)dh * S_LEN + key0 + ((lin & 127) >> 1),
                  vbuf + (p >> 1));
      }
    };

    const int q0w = q0t + w * 16;
    short8 qf[4];
#pragma unroll
    for (int ks = 0; ks < 4; ++ks)
      qf[ks] = *(const short8*)(Q + sbh + (size_t)(q0w + ec) * DHEAD + ks * 32 + er * 8);

    const unsigned selq = selS[w * 16 + ec];  // this lane's query sel mask
    const int qmine = q0w + ec;

    const f32x4 fz = {0.f, 0.f, 0.f, 0.f};
    f32x4 oacc[8];
#pragma unroll
    for (int n = 0; n < 8; ++n) oacc[n] = fz;
    float m = -1e30f, lrow = 0.f;
    short* pl = &plds[w][0];

    kstage(&kbuf[0][0], kbsS[0]);
    int cur = 0;
    for (int it = 0; it < nIter; ++it) {
      const int key0 = kbsS[it];
      const int kb = key0 >> 9;
      const int key0n = kbsS[(it + 1 < nIter) ? it + 1 : it];
      vstage(key0);
      kstage(&kbuf[cur ^ 1][0], key0n);
      asm volatile("s_waitcnt vmcnt(4)" ::: "memory");
      __builtin_amdgcn_sched_barrier(0);
      __builtin_amdgcn_s_barrier();
      __builtin_amdgcn_sched_barrier(0);

      // ---- QK^T swapped: D[row=key er*4+r][col=query ec]
      const short* kl = &kbuf[cur][0];
      float s[16];
#pragma unroll
      for (int kh = 0; kh < 4; ++kh) {
        short8 kf[4];
#pragma unroll
        for (int ks = 0; ks < 4; ++ks) {
          int slot = ((ks << 2) + er) ^ (ec & 7);
          kf[ks] = *(const short8*)(kl + (((kh << 4) + ec) << 7) + (slot << 3));
        }
        f32x4 a = fz;
#pragma unroll
        for (int ks = 0; ks < 4; ++ks) a = MFMA(kf[ks], qf[ks], a);
#pragma unroll
        for (int r = 0; r < 4; ++r) s[kh * 4 + r] = a[r];
      }

      // ---- masks + row max (this lane's query)
      int kqoff = qmine - key0 - er4;  // visible iff kh*16 + r <= kqoff
      if (!((selq >> kb) & 1)) kqoff = -1;
      float mx = -1e30f;
#pragma unroll
      for (int kh = 0; kh < 4; ++kh)
#pragma unroll
        for (int r = 0; r < 4; ++r)
          mx = fmaxf(mx, ((kh * 16 + r) <= kqoff) ? s[kh * 4 + r] : -1e30f);
      mx = fmaxf(mx, __shfl_xor(mx, 16, 64));
      mx = fmaxf(mx, __shfl_xor(mx, 32, 64));

      // ---- defer-max rescale (rare)
      if (__any(mx > m + 62.0f)) {
        float mnew = fmaxf(m, mx);
        float corr = __builtin_amdgcn_exp2f((m - mnew) * C);
        m = mnew;
        lrow *= corr;
        float c0 = __shfl(corr, er4 + 0, 16);
        float c1 = __shfl(corr, er4 + 1, 16);
        float c2 = __shfl(corr, er4 + 2, 16);
        float c3 = __shfl(corr, er4 + 3, 16);
#pragma unroll
        for (int n = 0; n < 8; ++n) {
          oacc[n][0] *= c0;
          oacc[n][1] *= c1;
          oacc[n][2] *= c2;
          oacc[n][3] *= c3;
        }
      }

      // ---- exp + sum
      const float mc = m * C;
      float e[16];
      float rs = 0.f;
#pragma unroll
      for (int kh = 0; kh < 4; ++kh)
#pragma unroll
        for (int r = 0; r < 4; ++r) {
          int i = kh * 4 + r;
          float ex = __builtin_amdgcn_exp2f(fmaf(s[i], C, -mc));
          ex = ((kh * 16 + r) <= kqoff) ? ex : 0.f;
          e[i] = ex;
          rs += ex;
        }
      rs += __shfl_xor(rs, 16, 64);
      rs += __shfl_xor(rs, 32, 64);
      lrow += rs;

      // ---- pack P (bf16 pairs, lane-local consecutive keys)
      short* pb = pl + ec * 72 + er4;
#pragma unroll
      for (int kh = 0; kh < 4; ++kh) {
        unsigned u0, u1;
        asm("v_cvt_pk_bf16_f32 %0, %1, %2"
            : "=v"(u0) : "v"(e[kh * 4 + 0]), "v"(e[kh * 4 + 1]));
        asm("v_cvt_pk_bf16_f32 %0, %1, %2"
            : "=v"(u1) : "v"(e[kh * 4 + 2]), "v"(e[kh * 4 + 3]));
        *(unsigned*)(pb + kh * 16) = u0;
        *(unsigned*)(pb + kh * 16 + 2) = u1;
      }
      asm volatile("s_waitcnt lgkmcnt(0)" ::: "memory");
      __builtin_amdgcn_sched_barrier(0);
      const short8 pa0 = *(const short8*)(pl + ec * 72 + er * 8);
      const short8 pa1 = *(const short8*)(pl + ec * 72 + 32 + er * 8);

      asm volatile("s_waitcnt vmcnt(2)" ::: "memory");
      __builtin_amdgcn_sched_barrier(0);
      __builtin_amdgcn_s_barrier();
      __builtin_amdgcn_sched_barrier(0);

      // ---- PV over 64 keys
#pragma unroll
      for (int kc = 0; kc < 2; ++kc) {
        const short8 pa = kc ? pa1 : pa0;
#pragma unroll
        for (int n = 0; n < 8; ++n) {
          int slot = ((kc << 2) + er) ^ (ec & 7);
          short8 vf = *(const short8*)(vbuf + (((n << 4) + ec) << 6) + (slot << 3));
          oacc[n] = MFMA(pa, vf, oacc[n]);
        }
      }
      __builtin_amdgcn_sched_barrier(0);
      __builtin_amdgcn_s_barrier();
      __builtin_amdgcn_sched_barrier(0);
      cur ^= 1;
    }

    // ---- epilogue: gather per-row l, write out
    float rl[4];
#pragma unroll
    for (int r = 0; r < 4; ++r) rl[r] = 1.0f / __shfl(lrow, er4 + r, 16);
#pragma unroll
    for (int n = 0; n < 8; ++n) {
#pragma unroll
      for (int r = 0; r < 4; ++r) {
        float v = oacc[n][r] * rl[r];
        out[((size_t)(b * S_LEN + q0w + er4 + r)) * DMODEL + h * DHEAD + n * 16 + ec] = f2bf(v);
      }
    }
    asm volatile("s_waitcnt vmcnt(0)" ::: "memory");
    __syncthreads();
  }
}

// ---------------------------------------------------------------- launcher
extern "C" void kernel_launch(void* const* d_in, const int* in_sizes, int n_in,
                              void* d_out, int out_size, void* d_ws,
                              size_t ws_size, hipStream_t stream) {
  (void)in_sizes; (void)n_in; (void)out_size; (void)ws_size;
  const float* hidden = (const float*)d_in[0];
  const float* ln1w = (const float*)d_in[1];
  const float* ln1b = (const float*)d_in[2];
  const float* wq = (const float*)d_in[3];
  const float* bq = (const float*)d_in[4];
  const float* wk = (const float*)d_in[5];
  const float* bk = (const float*)d_in[6];
  const float* wv = (const float*)d_in[7];
  const float* bv = (const float*)d_in[8];
  const float* wo = (const float*)d_in[9];
  const float* bo = (const float*)d_in[10];
  const float* ln2w = (const float*)d_in[11];
  const float* ln2b = (const float*)d_in[12];
  const float* wi = (const float*)d_in[13];
  const float* bi = (const float*)d_in[14];
  const float* wo2 = (const float*)d_in[15];
  const float* bo2 = (const float*)d_in[16];
  const float* cosT = (const float*)d_in[17];
  const float* sinT = (const float*)d_in[18];
  float* outF = (float*)d_out;

  char* base = (char*)d_ws;
  size_t off = 0;
  auto alloc = [&](size_t bytes) {
    char* p = base + off;
    off = (off + bytes + 255) & ~(size_t)255;
    return p;
  };
  short* wqkvT = (short*)alloc((size_t)3072 * 1024 * 2);
  short* woT = (short*)alloc((size_t)1024 * 1024 * 2);
  short* wiT = (short*)alloc((size_t)4096 * 1024 * 2);
  short* wo2T = (short*)alloc((size_t)1024 * 4096 * 2);
  float* biasC = (float*)alloc((size_t)3072 * 4);
  float* kmeanB = (float*)alloc((size_t)16 * 8 * 128 * 4);
  unsigned* selm = (unsigned*)alloc((size_t)16 * 4096 * 4);
  short* xattn = (short*)alloc((size_t)8192 * 1024 * 2);
  short* h2 = (short*)alloc((size_t)8192 * 1024 * 2);
  size_t phase = off;
  short* xln = (short*)alloc((size_t)8192 * 1024 * 2);
  short* qb = (short*)alloc((size_t)16 * 4096 * 128 * 2);
  short* kb = (short*)alloc((size_t)16 * 4096 * 128 * 2);
  short* vb = (short*)alloc((size_t)16 * 4096 * 128 * 2);
  short* vT = (short*)alloc((size_t)16 * 128 * 4096 * 2);
  short* g = (short*)(base + phase);

  dim3 T256(256);
  dim3 T512(512);
  transpose_bf16<float><<<dim3(32, 32, 1), T256, 0, stream>>>(wq, wqkvT, 1024, 1024);
  transpose_bf16<float><<<dim3(32, 32, 1), T256, 0, stream>>>(wk, wqkvT + 1048576, 1024, 1024);
  transpose_bf16<float><<<dim3(32, 32, 1), T256, 0, stream>>>(wv, wqkvT + 2097152, 1024, 1024);
  transpose_bf16<float><<<dim3(32, 32, 1), T256, 0, stream>>>(wo, woT, 1024, 1024);
  transpose_bf16<float><<<dim3(128, 32, 1), T256, 0, stream>>>(wi, wiT, 1024, 4096);
  transpose_bf16<float><<<dim3(32, 128, 1), T256, 0, stream>>>(wo2, wo2T, 4096, 1024);
  pack_bias<<<12, T256, 0, stream>>>(bq, bk, bv, biasC);

  ln_kernel<<<2048, T256, 0, stream>>>(hidden, ln1w, ln1b, xln);

  gemm256<256, 2, 4><<<dim3(12, 32), T512, 0, stream>>>(xln, wqkvT, biasC, nullptr, qb, nullptr, 8192, 3072, 1024);

  rope_kernel<<<16384, T256, 0, stream>>>(qb, kb, cosT, sinT);
  transpose_bf16<short><<<dim3(4, 128, 16), T256, 0, stream>>>(vb, vT, 4096, 128);

  kmean_kernel<<<dim3(8, 16), T256, 0, stream>>>(kb, kmeanB);
  gate_kernel<<<256, T256, 0, stream>>>(qb, kmeanB, selm);

  attn_kernel<<<dim3(256), T512, 0, stream>>>(qb, kb, vT, selm, xattn);

  gemm256<128, 4, 1><<<dim3(8, 32), T512, 0, stream>>>(xattn, woT, bo, hidden, nullptr, outF, 8192, 1024, 1024);
  ln_kernel<<<2048, T256, 0, stream>>>(outF, ln2w, ln2b, h2);
  gemm256<256, 2, 2><<<dim3(16, 32), T512, 0, stream>>>(h2, wiT, bi, nullptr, g, nullptr, 8192, 4096, 1024);
  gemm256<128, 4, 3><<<dim3(8, 32), T512, 0, stream>>>(g, wo2T, bo2, nullptr, nullptr, outF, 8192, 1024, 4096);
}

// Round 7
// 642.523 us; speedup vs baseline: 2.4468x; 1.0505x over previous
//
#include <hip/hip_runtime.h>
#include <cstdint>

#define S_LEN 4096
#define NHEAD 8
#define DHEAD 128
#define DMODEL 1024
#define MOBA_TOPK 4

typedef __attribute__((ext_vector_type(8))) short short8;
typedef __attribute__((ext_vector_type(4))) float f32x4;

__device__ inline float bf2f(short s) {
  return __builtin_bit_cast(float, (unsigned)((unsigned short)s) << 16);
}
__device__ inline short f2bf(float f) {
  unsigned u = __builtin_bit_cast(unsigned, f);
  unsigned r = (u + 0x7fffu + ((u >> 16) & 1u)) >> 16;
  return (short)(unsigned short)r;
}

#define MFMA(a, b, c) __builtin_amdgcn_mfma_f32_16x16x32_bf16(a, b, c, 0, 0, 0)
#define GLOAD_LDS(gsrc, ldst)                                                  \
  __builtin_amdgcn_global_load_lds(                                            \
      (const __attribute__((address_space(1))) void*)(gsrc),                   \
      (__attribute__((address_space(3))) void*)(ldst), 16, 0, 0)

// ---------------------------------------------------------------- prep
// All weight transposes (fp32 [R,C] -> bf16 [C,R]) + bias concat, one kernel.
__global__ __launch_bounds__(256) void prep_kernel(
    const float* __restrict__ wq, const float* __restrict__ wk,
    const float* __restrict__ wv, const float* __restrict__ wo,
    const float* __restrict__ wi, const float* __restrict__ wo2,
    const float* __restrict__ bq, const float* __restrict__ bk,
    const float* __restrict__ bv, short* __restrict__ wqkvT,
    short* __restrict__ woT, short* __restrict__ wiT,
    short* __restrict__ wo2T, float* __restrict__ biasC) {
  __shared__ float tile[32][33];
  const int b = blockIdx.x;
  const int tx = threadIdx.x & 31, ty = threadIdx.x >> 5;
  const float* in;
  short* out;
  int R, C, bx, by;
  if (b < 3072) {
    int seg = b >> 10, idx = b & 1023;
    in = seg == 0 ? wq : seg == 1 ? wk : wv;
    out = wqkvT + seg * 1048576;
    R = 1024; C = 1024; bx = idx & 31; by = idx >> 5;
  } else if (b < 4096) {
    int idx = b - 3072;
    in = wo; out = woT; R = 1024; C = 1024; bx = idx & 31; by = idx >> 5;
  } else if (b < 8192) {
    int idx = b - 4096;
    in = wi; out = wiT; R = 1024; C = 4096; bx = idx & 127; by = idx >> 7;
  } else if (b < 12288) {
    int idx = b - 8192;
    in = wo2; out = wo2T; R = 4096; C = 1024; bx = idx & 31; by = idx >> 5;
  } else {
    int i = (b - 12288) * 256 + threadIdx.x;
    if (i < 3072) {
      const float* src = (i < 1024) ? bq : (i < 2048) ? bk : bv;
      biasC[i] = src[i & 1023];
    }
    return;
  }
  int c0 = bx * 32, r0 = by * 32;
#pragma unroll
  for (int i = 0; i < 32; i += 8)
    tile[ty + i][tx] = in[(size_t)(r0 + ty + i) * C + c0 + tx];
  __syncthreads();
#pragma unroll
  for (int i = 0; i < 32; i += 8)
    out[(size_t)(c0 + ty + i) * R + r0 + tx] = f2bf(tile[tx][ty + i]);
}

// ---------------------------------------------------------------- layernorm
__global__ __launch_bounds__(256) void ln_kernel(const float* __restrict__ x,
                                                 const float* __restrict__ w,
                                                 const float* __restrict__ b,
                                                 short* __restrict__ out) {
  int row = blockIdx.x * 4 + (threadIdx.x >> 6);
  int lane = threadIdx.x & 63;
  const float* xr = x + (size_t)row * DMODEL + lane * 16;
  f32x4 v[4];
  float sum = 0.f, sq = 0.f;
#pragma unroll
  for (int i = 0; i < 4; ++i) {
    v[i] = *(const f32x4*)(xr + i * 4);
#pragma unroll
    for (int j = 0; j < 4; ++j) {
      sum += v[i][j];
      sq += v[i][j] * v[i][j];
    }
  }
#pragma unroll
  for (int d = 1; d < 64; d <<= 1) {
    sum += __shfl_xor(sum, d, 64);
    sq += __shfl_xor(sq, d, 64);
  }
  float mu = sum * (1.f / DMODEL);
  float var = sq * (1.f / DMODEL) - mu * mu;
  float rstd = rsqrtf(var + 1e-5f);
  short* orow = out + (size_t)row * DMODEL;
#pragma unroll
  for (int i = 0; i < 4; ++i)
#pragma unroll
    for (int j = 0; j < 4; ++j) {
      int c = lane * 16 + i * 4 + j;
      orow[c] = f2bf((v[i][j] - mu) * rstd * w[c] + b[c]);
    }
}

// ---------------------------------------------------------------- GEMM 256x BN
template <int BN, int WM, int MODE>
__global__ __launch_bounds__(512, 2) void gemm256(const short* __restrict__ A,
                                                  const short* __restrict__ BT,
                                                  const float* __restrict__ bias,
                                                  const float* __restrict__ residF,
                                                  short* __restrict__ outB,
                                                  float* outF, int M, int N,
                                                  int K) {
  constexpr int MF = 16 / WM;    // m-frags per wave
  constexpr int NWN = 8 / WM;    // waves along n
  constexpr int RB = BN / 64;    // B stage rounds
  __shared__ alignas(16) short As[2][16384];
  __shared__ alignas(16) short Bs[2][BN * 64];

  const int t = threadIdx.x, lane = t & 63, w = t >> 6;
  const int wm = w / NWN, wn = w % NWN;
  // XCD-aware bijective swizzle (nwg % 8 == 0 for all our grids)
  int bid = blockIdx.y * gridDim.x + blockIdx.x;
  const int chunk = (gridDim.x * gridDim.y) >> 3;
  bid = (bid & 7) * chunk + (bid >> 3);
  const int m0 = (bid / gridDim.x) * 256, n0 = (bid % gridDim.x) * BN;
  const int wmBase = wm * (256 / WM);
  const int wnBase = wn * 64;
  const int lr = lane & 15;
  const int koff0 = ((((lane >> 4) << 4)) ^ ((lane & 7) << 4)) >> 1;
  const int koff1 = ((64 + ((lane >> 4) << 4)) ^ ((lane & 7) << 4)) >> 1;

  const f32x4 fz = {0.f, 0.f, 0.f, 0.f};
  f32x4 acc[MF][4];
#pragma unroll
  for (int i = 0; i < MF; ++i)
#pragma unroll
    for (int j = 0; j < 4; ++j) acc[i][j] = fz;

  auto stageA = [&](short* dst, int k0) {
#pragma unroll
    for (int rd = 0; rd < 4; ++rd) {
      int p = (t << 4) + (rd << 13);
      int row = p >> 7;
      int ks = ((p & 127) ^ ((row & 7) << 4)) >> 1;
      GLOAD_LDS(A + (size_t)(m0 + row) * K + k0 + ks, dst + (p >> 1));
    }
  };
  auto stageB = [&](short* dst, int k0) {
#pragma unroll
    for (int rd = 0; rd < RB; ++rd) {
      int p = (t << 4) + (rd << 13);
      int row = p >> 7;
      int ks = ((p & 127) ^ ((row & 7) << 4)) >> 1;
      GLOAD_LDS(BT + (size_t)(n0 + row) * K + k0 + ks, dst + (p >> 1));
    }
  };

  const int NT = K >> 6;
  stageA(&As[0][0], 0);
  stageB(&Bs[0][0], 0);
  __syncthreads();

  for (int kt = 0; kt < NT; ++kt) {
    const int cur = kt & 1;
    if (kt + 1 < NT) {
      stageA(&As[cur ^ 1][0], (kt + 1) << 6);
      stageB(&Bs[cur ^ 1][0], (kt + 1) << 6);
    }
    __builtin_amdgcn_sched_barrier(0);
    short8 bfr[4][2];
#pragma unroll
    for (int ni = 0; ni < 4; ++ni) {
      int rb = (wnBase + ni * 16 + lr) << 6;
      bfr[ni][0] = *(const short8*)(&Bs[cur][rb + koff0]);
      bfr[ni][1] = *(const short8*)(&Bs[cur][rb + koff1]);
    }
#pragma unroll
    for (int pp = 0; pp < MF / 2; ++pp) {
      const int ra0 = (wmBase + (pp * 2) * 16 + lr) << 6;
      const int ra1 = (wmBase + (pp * 2 + 1) * 16 + lr) << 6;
      short8 a00 = *(const short8*)(&As[cur][ra0 + koff0]);
      short8 a01 = *(const short8*)(&As[cur][ra0 + koff1]);
      short8 a10 = *(const short8*)(&As[cur][ra1 + koff0]);
      short8 a11 = *(const short8*)(&As[cur][ra1 + koff1]);
      __builtin_amdgcn_sched_barrier(0);
      __builtin_amdgcn_s_setprio(1);
#pragma unroll
      for (int ni = 0; ni < 4; ++ni) {
        acc[pp * 2][ni] = MFMA(a00, bfr[ni][0], acc[pp * 2][ni]);
        acc[pp * 2][ni] = MFMA(a01, bfr[ni][1], acc[pp * 2][ni]);
        acc[pp * 2 + 1][ni] = MFMA(a10, bfr[ni][0], acc[pp * 2 + 1][ni]);
        acc[pp * 2 + 1][ni] = MFMA(a11, bfr[ni][1], acc[pp * 2 + 1][ni]);
      }
      __builtin_amdgcn_s_setprio(0);
      __builtin_amdgcn_sched_barrier(0);
    }
    __syncthreads();
  }

  const int er = lane >> 4, ec = lane & 15;
#pragma unroll
  for (int mi = 0; mi < MF; ++mi) {
#pragma unroll
    for (int ni = 0; ni < 4; ++ni) {
      int col = n0 + wnBase + ni * 16 + ec;
      float bs = bias[col];
#pragma unroll
      for (int r = 0; r < 4; ++r) {
        int row = m0 + wmBase + mi * 16 + er * 4 + r;
        float v = acc[mi][ni][r] + bs;
        size_t idx = (size_t)row * N + col;
        if (MODE == 1) {
          v += residF[idx];
          outF[idx] = v;
        } else if (MODE == 2) {
          float gl = 0.5f * v * (1.f + erff(v * 0.70710678118654752f));
          outB[idx] = f2bf(gl);
        } else if (MODE == 3) {
          v += outF[idx];
          outF[idx] = v;
        } else {
          int b = row >> 12, s = row & 4095;
          int tens = col >> 10, rem = col & 1023;
          int h = rem >> 7, dh = rem & 127;
          outB[(size_t)tens * 8388608 +
               ((size_t)((b * NHEAD + h) * S_LEN + s)) * DHEAD + dh] = f2bf(v);
        }
      }
    }
  }
}

// ---------------------------------------------------------------- rope + vT
// blocks [0,16384): RoPE on q,k (4 rows/block).
// blocks [16384,24576): transpose vb [4096,128] -> vT [128,4096] per bh.
__global__ __launch_bounds__(256) void ropevt_kernel(
    short* __restrict__ q, short* __restrict__ k,
    const short* __restrict__ vb, short* __restrict__ vT,
    const float* __restrict__ cosT, const float* __restrict__ sinT) {
  __shared__ float tile[32][33];
  const int b = blockIdx.x;
  if (b < 16384) {
    int row = b * 4 + (threadIdx.x >> 6);
    int lane = threadIdx.x & 63;
    int s = row & (S_LEN - 1);
    float c1 = cosT[s * DHEAD + lane], s1 = sinT[s * DHEAD + lane];
    float c2 = cosT[s * DHEAD + 64 + lane], s2 = sinT[s * DHEAD + 64 + lane];
    size_t base = (size_t)row * DHEAD;
    float a = bf2f(q[base + lane]), bb = bf2f(q[base + 64 + lane]);
    q[base + lane] = f2bf(a * c1 - bb * s1);
    q[base + 64 + lane] = f2bf(bb * c2 + a * s2);
    a = bf2f(k[base + lane]);
    bb = bf2f(k[base + 64 + lane]);
    k[base + lane] = f2bf(a * c1 - bb * s1);
    k[base + 64 + lane] = f2bf(bb * c2 + a * s2);
    return;
  }
  int idx = b - 16384;
  int bz = idx >> 9, rem = idx & 511;
  int bx = rem & 3, by = rem >> 2;
  size_t bo = (size_t)bz * S_LEN * DHEAD;
  int c0 = bx * 32, r0 = by * 32;
  int tx = threadIdx.x & 31, ty = threadIdx.x >> 5;
#pragma unroll
  for (int i = 0; i < 32; i += 8)
    tile[ty + i][tx] = bf2f(vb[bo + (size_t)(r0 + ty + i) * DHEAD + c0 + tx]);
  __syncthreads();
#pragma unroll
  for (int i = 0; i < 32; i += 8)
    vT[bo + (size_t)(c0 + ty + i) * S_LEN + r0 + tx] = f2bf(tile[tx][ty + i]);
}

// ---------------------------------------------------------------- kmean
__global__ __launch_bounds__(256) void kmean_kernel(const short* __restrict__ K,
                                                    float* __restrict__ kmean) {
  int n = blockIdx.x, bh = blockIdx.y;
  int t = threadIdx.x;
  int d = t & 127, half = t >> 7;
  const short* base = K + ((size_t)bh * S_LEN + n * 512 + half * 256) * DHEAD + d;
  float s = 0.f;
  for (int i = 0; i < 256; ++i) s += bf2f(base[(size_t)i * DHEAD]);
  __shared__ float red[256];
  red[t] = s;
  __syncthreads();
  if (t < 128)
    kmean[((size_t)bh * 8 + n) * DHEAD + d] = (red[t] + red[t + 128]) * (1.f / 512.f);
}

// ---------------------------------------------------------------- gate / topk
__global__ __launch_bounds__(256) void gate_kernel(const short* __restrict__ Q,
                                                   const float* __restrict__ kmean,
                                                   unsigned* __restrict__ selmask) {
  int bh = blockIdx.x >> 4;
  int s = ((blockIdx.x & 15) << 8) + threadIdx.x;
  __shared__ float km[8 * DHEAD];
  for (int i = threadIdx.x; i < 8 * DHEAD; i += 256)
    km[i] = kmean[(size_t)bh * 8 * DHEAD + i];
  __syncthreads();
  const short* qrow = Q + ((size_t)bh * S_LEN + s) * DHEAD;
  float g[8] = {0, 0, 0, 0, 0, 0, 0, 0};
  for (int c = 0; c < 16; ++c) {
    short8 qv = *(const short8*)(qrow + c * 8);
    float qf[8];
#pragma unroll
    for (int j = 0; j < 8; ++j) qf[j] = bf2f(qv[j]);
#pragma unroll
    for (int n = 0; n < 8; ++n) {
      float a = 0.f;
#pragma unroll
      for (int j = 0; j < 8; ++j) a += qf[j] * km[n * DHEAD + c * 8 + j];
      g[n] += a;
    }
  }
  int own = s >> 9;
  int nvis = own + 1;
  int kcnt = nvis < MOBA_TOPK ? nvis : MOBA_TOPK;
  unsigned used = 0;
  for (int it = 0; it < kcnt; ++it) {
    float best = -1e38f;
    int bi = 0;
    for (int n = 0; n < nvis; ++n)
      if (!((used >> n) & 1) && g[n] > best) {
        best = g[n];
        bi = n;
      }
    used |= 1u << bi;
  }
  selmask[(size_t)bh * S_LEN + s] = used | (1u << own);
}

// ---------------------------------------------------------------- attention
// grid=512, 1 unit/block, 2 blocks/CU. Pairing u = bid<256 ? bid : 767-bid
// puts complementary causal loads (qt, 31-qt) on co-resident blocks.
__global__ __launch_bounds__(512, 4) void attn_kernel(
    const short* __restrict__ Q, const short* __restrict__ K,
    const short* __restrict__ VT, const unsigned* __restrict__ selmask,
    short* __restrict__ out) {
  const int t = threadIdx.x, lane = t & 63, w = t >> 6;
  const int er = lane >> 4, ec = lane & 15;
  const int er4 = er << 2;

  __shared__ alignas(16) short kbuf[2][8192];
  __shared__ alignas(16) short vbuf[8192];
  __shared__ alignas(16) short plds[8][1152];
  __shared__ unsigned selS[128];
  __shared__ unsigned umS[2];
  __shared__ int kbsS[66];

  const float C = 0.12751742946f;  // log2(e)/sqrt(128)

  const int bid = blockIdx.x;
  const int u = (bid < 256) ? bid : 767 - bid;
  const int qt = u & 31, bh = u >> 5;
  const int b = bh >> 3, h = bh & 7;
  const int q0t = qt << 7;

  if (t < 128) selS[t] = selmask[(size_t)bh * S_LEN + q0t + t];
  __syncthreads();
  if (w < 2) {
    unsigned v = selS[w * 64 + lane];
#pragma unroll
    for (int d = 1; d < 64; d <<= 1) v |= __shfl_xor(v, d, 64);
    if (lane == 0) umS[w] = v;
  }
  __syncthreads();
  if (t == 0) {
    unsigned um = umS[0] | umS[1];
    int qmax = q0t + 127;
    int maxb = qmax >> 9;
    int n = 0;
    for (int kb = 0; kb <= maxb; ++kb)
      if ((um >> kb) & 1) {
        int subs = (kb == maxb) ? (((qmax - (kb << 9)) >> 6) + 1) : 8;
        for (int s2 = 0; s2 < subs; ++s2) kbsS[n++] = (kb << 9) + (s2 << 6);
      }
    kbsS[64] = n;
  }
  __syncthreads();
  const int nIter = kbsS[64];

  const size_t sbh = (size_t)bh * S_LEN * DHEAD;
  const short* Kg = K + sbh;
  const short* Vg = VT + (size_t)bh * DHEAD * S_LEN;

  auto kstage = [&](short* dst, int key0) {
#pragma unroll
    for (int rnd = 0; rnd < 2; ++rnd) {
      int p = (t + rnd * 512) << 4;
      int key = p >> 8;
      int lin = p ^ ((key & 7) << 4);
      GLOAD_LDS(Kg + (size_t)(key0 + key) * DHEAD + ((lin & 255) >> 1),
                dst + (p >> 1));
    }
  };
  auto vstage = [&](int key0) {
#pragma unroll
    for (int rnd = 0; rnd < 2; ++rnd) {
      int p = (t + rnd * 512) << 4;
      int dh = p >> 7;
      int lin = p ^ ((dh & 7) << 4);
      GLOAD_LDS(Vg + (size_t)dh * S_LEN + key0 + ((lin & 127) >> 1),
                vbuf + (p >> 1));
    }
  };

  const int q0w = q0t + w * 16;
  short8 qf[4];
#pragma unroll
  for (int ks = 0; ks < 4; ++ks)
    qf[ks] = *(const short8*)(Q + sbh + (size_t)(q0w + ec) * DHEAD + ks * 32 + er * 8);

  const unsigned selq = selS[w * 16 + ec];
  const int qmine = q0w + ec;

  const f32x4 fz = {0.f, 0.f, 0.f, 0.f};
  f32x4 oacc[8];
#pragma unroll
  for (int n = 0; n < 8; ++n) oacc[n] = fz;
  float m = -1e30f, lrow = 0.f;
  short* pl = &plds[w][0];

  kstage(&kbuf[0][0], kbsS[0]);
  int cur = 0;
  for (int it = 0; it < nIter; ++it) {
    const int key0 = kbsS[it];
    const int kb = key0 >> 9;
    const int key0n = kbsS[(it + 1 < nIter) ? it + 1 : it];
    vstage(key0);
    kstage(&kbuf[cur ^ 1][0], key0n);
    asm volatile("s_waitcnt vmcnt(4)" ::: "memory");
    __builtin_amdgcn_sched_barrier(0);
    __builtin_amdgcn_s_barrier();
    __builtin_amdgcn_sched_barrier(0);

    // ---- QK^T swapped: D[row=key er*4+r][col=query ec]
    const short* kl = &kbuf[cur][0];
    float s[16];
#pragma unroll
    for (int kh = 0; kh < 4; ++kh) {
      short8 kf[4];
#pragma unroll
      for (int ks = 0; ks < 4; ++ks) {
        int slot = ((ks << 2) + er) ^ (ec & 7);
        kf[ks] = *(const short8*)(kl + (((kh << 4) + ec) << 7) + (slot << 3));
      }
      f32x4 a = fz;
#pragma unroll
      for (int ks = 0; ks < 4; ++ks) a = MFMA(kf[ks], qf[ks], a);
#pragma unroll
      for (int r = 0; r < 4; ++r) s[kh * 4 + r] = a[r];
    }

    // ---- masks + row max (this lane's query)
    int kqoff = qmine - key0 - er4;
    if (!((selq >> kb) & 1)) kqoff = -1;
    float mx = -1e30f;
#pragma unroll
    for (int kh = 0; kh < 4; ++kh)
#pragma unroll
      for (int r = 0; r < 4; ++r)
        mx = fmaxf(mx, ((kh * 16 + r) <= kqoff) ? s[kh * 4 + r] : -1e30f);
    mx = fmaxf(mx, __shfl_xor(mx, 16, 64));
    mx = fmaxf(mx, __shfl_xor(mx, 32, 64));

    // ---- defer-max rescale (rare)
    if (__any(mx > m + 62.0f)) {
      float mnew = fmaxf(m, mx);
      float corr = __builtin_amdgcn_exp2f((m - mnew) * C);
      m = mnew;
      lrow *= corr;
      float c0 = __shfl(corr, er4 + 0, 16);
      float c1 = __shfl(corr, er4 + 1, 16);
      float c2 = __shfl(corr, er4 + 2, 16);
      float c3 = __shfl(corr, er4 + 3, 16);
#pragma unroll
      for (int n = 0; n < 8; ++n) {
        oacc[n][0] *= c0;
        oacc[n][1] *= c1;
        oacc[n][2] *= c2;
        oacc[n][3] *= c3;
      }
    }

    // ---- exp + sum
    const float mc = m * C;
    float e[16];
    float rs = 0.f;
#pragma unroll
    for (int kh = 0; kh < 4; ++kh)
#pragma unroll
      for (int r = 0; r < 4; ++r) {
        int i = kh * 4 + r;
        float ex = __builtin_amdgcn_exp2f(fmaf(s[i], C, -mc));
        ex = ((kh * 16 + r) <= kqoff) ? ex : 0.f;
        e[i] = ex;
        rs += ex;
      }
    rs += __shfl_xor(rs, 16, 64);
    rs += __shfl_xor(rs, 32, 64);
    lrow += rs;

    // ---- pack P (bf16 pairs, lane-local consecutive keys)
    short* pb = pl + ec * 72 + er4;
#pragma unroll
    for (int kh = 0; kh < 4; ++kh) {
      unsigned u0, u1;
      asm("v_cvt_pk_bf16_f32 %0, %1, %2"
          : "=v"(u0) : "v"(e[kh * 4 + 0]), "v"(e[kh * 4 + 1]));
      asm("v_cvt_pk_bf16_f32 %0, %1, %2"
          : "=v"(u1) : "v"(e[kh * 4 + 2]), "v"(e[kh * 4 + 3]));
      *(unsigned*)(pb + kh * 16) = u0;
      *(unsigned*)(pb + kh * 16 + 2) = u1;
    }
    asm volatile("s_waitcnt lgkmcnt(0)" ::: "memory");
    __builtin_amdgcn_sched_barrier(0);
    const short8 pa0 = *(const short8*)(pl + ec * 72 + er * 8);
    const short8 pa1 = *(const short8*)(pl + ec * 72 + 32 + er * 8);

    asm volatile("s_waitcnt vmcnt(2)" ::: "memory");
    __builtin_amdgcn_sched_barrier(0);
    __builtin_amdgcn_s_barrier();
    __builtin_amdgcn_sched_barrier(0);

    // ---- PV over 64 keys
#pragma unroll
    for (int kc = 0; kc < 2; ++kc) {
      const short8 pa = kc ? pa1 : pa0;
#pragma unroll
      for (int n = 0; n < 8; ++n) {
        int slot = ((kc << 2) + er) ^ (ec & 7);
        short8 vf = *(const short8*)(vbuf + (((n << 4) + ec) << 6) + (slot << 3));
        oacc[n] = MFMA(pa, vf, oacc[n]);
      }
    }
    __builtin_amdgcn_sched_barrier(0);
    __builtin_amdgcn_s_barrier();
    __builtin_amdgcn_sched_barrier(0);
    cur ^= 1;
  }

  // ---- epilogue: gather per-row l, write out
  float rl[4];
#pragma unroll
  for (int r = 0; r < 4; ++r) rl[r] = 1.0f / __shfl(lrow, er4 + r, 16);
#pragma unroll
  for (int n = 0; n < 8; ++n) {
#pragma unroll
    for (int r = 0; r < 4; ++r) {
      float v = oacc[n][r] * rl[r];
      out[((size_t)(b * S_LEN + q0w + er4 + r)) * DMODEL + h * DHEAD + n * 16 + ec] = f2bf(v);
    }
  }
  asm volatile("s_waitcnt vmcnt(0)" ::: "memory");
}

// ---------------------------------------------------------------- launcher
extern "C" void kernel_launch(void* const* d_in, const int* in_sizes, int n_in,
                              void* d_out, int out_size, void* d_ws,
                              size_t ws_size, hipStream_t stream) {
  (void)in_sizes; (void)n_in; (void)out_size; (void)ws_size;
  const float* hidden = (const float*)d_in[0];
  const float* ln1w = (const float*)d_in[1];
  const float* ln1b = (const float*)d_in[2];
  const float* wq = (const float*)d_in[3];
  const float* bq = (const float*)d_in[4];
  const float* wk = (const float*)d_in[5];
  const float* bk = (const float*)d_in[6];
  const float* wv = (const float*)d_in[7];
  const float* bv = (const float*)d_in[8];
  const float* wo = (const float*)d_in[9];
  const float* bo = (const float*)d_in[10];
  const float* ln2w = (const float*)d_in[11];
  const float* ln2b = (const float*)d_in[12];
  const float* wi = (const float*)d_in[13];
  const float* bi = (const float*)d_in[14];
  const float* wo2 = (const float*)d_in[15];
  const float* bo2 = (const float*)d_in[16];
  const float* cosT = (const float*)d_in[17];
  const float* sinT = (const float*)d_in[18];
  float* outF = (float*)d_out;

  char* base = (char*)d_ws;
  size_t off = 0;
  auto alloc = [&](size_t bytes) {
    char* p = base + off;
    off = (off + bytes + 255) & ~(size_t)255;
    return p;
  };
  short* wqkvT = (short*)alloc((size_t)3072 * 1024 * 2);
  short* woT = (short*)alloc((size_t)1024 * 1024 * 2);
  short* wiT = (short*)alloc((size_t)4096 * 1024 * 2);
  short* wo2T = (short*)alloc((size_t)1024 * 4096 * 2);
  float* biasC = (float*)alloc((size_t)3072 * 4);
  float* kmeanB = (float*)alloc((size_t)16 * 8 * 128 * 4);
  unsigned* selm = (unsigned*)alloc((size_t)16 * 4096 * 4);
  short* xattn = (short*)alloc((size_t)8192 * 1024 * 2);
  short* h2 = (short*)alloc((size_t)8192 * 1024 * 2);
  size_t phase = off;
  short* xln = (short*)alloc((size_t)8192 * 1024 * 2);
  short* qb = (short*)alloc((size_t)16 * 4096 * 128 * 2);
  short* kb = (short*)alloc((size_t)16 * 4096 * 128 * 2);
  short* vb = (short*)alloc((size_t)16 * 4096 * 128 * 2);
  short* vT = (short*)alloc((size_t)16 * 128 * 4096 * 2);
  short* g = (short*)(base + phase);

  dim3 T256(256);
  dim3 T512(512);
  prep_kernel<<<12301, T256, 0, stream>>>(wq, wk, wv, wo, wi, wo2, bq, bk, bv,
                                          wqkvT, woT, wiT, wo2T, biasC);

  ln_kernel<<<2048, T256, 0, stream>>>(hidden, ln1w, ln1b, xln);

  gemm256<128, 4, 4><<<dim3(24, 32), T512, 0, stream>>>(xln, wqkvT, biasC, nullptr, qb, nullptr, 8192, 3072, 1024);

  ropevt_kernel<<<24576, T256, 0, stream>>>(qb, kb, vb, vT, cosT, sinT);

  kmean_kernel<<<dim3(8, 16), T256, 0, stream>>>(kb, kmeanB);
  gate_kernel<<<256, T256, 0, stream>>>(qb, kmeanB, selm);

  attn_kernel<<<dim3(512), T512, 0, stream>>>(qb, kb, vT, selm, xattn);

  gemm256<128, 4, 1><<<dim3(8, 32), T512, 0, stream>>>(xattn, woT, bo, hidden, nullptr, outF, 8192, 1024, 1024);
  ln_kernel<<<2048, T256, 0, stream>>>(outF, ln2w, ln2b, h2);
  gemm256<256, 2, 2><<<dim3(16, 32), T512, 0, stream>>>(h2, wiT, bi, nullptr, g, nullptr, 8192, 4096, 1024);
  gemm256<128, 4, 3><<<dim3(8, 32), T512, 0, stream>>>(g, wo2T, bo2, nullptr, nullptr, outF, 8192, 1024, 4096);
}